// Round 21
// baseline (342.259 us; speedup 1.0000x reference)
//
#include <hip/hip_runtime.h>
#include <math.h>

typedef float2 cf;

__device__ __forceinline__ cf cadd(cf a, cf b){ return make_float2(a.x+b.x, a.y+b.y); }
__device__ __forceinline__ cf csub(cf a, cf b){ return make_float2(a.x-b.x, a.y-b.y); }
__device__ __forceinline__ cf cmul(cf a, cf b){ return make_float2(a.x*b.x - a.y*b.y, a.x*b.y + a.y*b.x); }

__device__ __forceinline__ int SW(int i){ return i ^ ((i>>4)&15); }
#define AT(x) s[SW(x)]
#define WFENCE asm volatile("" ::: "memory")

template<bool WAVE> __device__ __forceinline__ void SYf(){
  if constexpr (WAVE) { WFENCE; } else __syncthreads();
}

// bins of U1sf needed downstream for first-order filter i
__device__ __forceinline__ int devB(int i){
  int jm = i/10 + 2;
  double kc = 900.0*exp2((double)(-jm));
  double sg = fmax(180.0*exp2((double)(-jm)), 2.0);
  return min(2000, (int)ceil(kc + 6.5*sg) + 1);
}

// ---------------- mixed-radix FFT stages (DIF fwd / DIT inv) -------------
template<int N, int L, bool INV>
__device__ __forceinline__ void stage_r2(cf* __restrict__ s, const cf* __restrict__ tw, int tid, int nt){
  constexpr int Ls = L/2, nbf = N/2, tws = 16000/L;
  for (int q = tid; q < nbf; q += nt){
    int blk = q / Ls, j = q - blk*Ls;
    int base = blk*L + j;
    cf w1 = tw[tws*j]; if (INV) w1.y = -w1.y;
    if (!INV){
      cf a = AT(base), b = AT(base+Ls);
      AT(base) = cadd(a,b);
      AT(base+Ls) = cmul(csub(a,b), w1);
    } else {
      cf a = AT(base), b = cmul(AT(base+Ls), w1);
      AT(base) = cadd(a,b);
      AT(base+Ls) = csub(a,b);
    }
  }
}

template<int N, int L, bool INV>
__device__ __forceinline__ void stage_r4(cf* __restrict__ s, const cf* __restrict__ tw, int tid, int nt){
  constexpr int Ls = L/4, nbf = N/4, tws = 16000/L;
  for (int q = tid; q < nbf; q += nt){
    int blk = q / Ls, j = q - blk*Ls;
    int base = blk*L + j;
    cf w1 = tw[tws*j]; if (INV) w1.y = -w1.y;
    cf w2 = cmul(w1,w1), w3 = cmul(w2,w1);
    if (!INV){
      cf y0=AT(base), y1=AT(base+Ls), y2=AT(base+2*Ls), y3=AT(base+3*Ls);
      cf t0=cadd(y0,y2), t1=csub(y0,y2), t2=cadd(y1,y3), t3=csub(y1,y3);
      AT(base)      = cadd(t0,t2);
      AT(base+Ls)   = cmul(make_float2(t1.x + t3.y, t1.y - t3.x), w1);
      AT(base+2*Ls) = cmul(csub(t0,t2), w2);
      AT(base+3*Ls) = cmul(make_float2(t1.x - t3.y, t1.y + t3.x), w3);
    } else {
      cf z0=AT(base);
      cf z1=cmul(AT(base+Ls),   w1);
      cf z2=cmul(AT(base+2*Ls), w2);
      cf z3=cmul(AT(base+3*Ls), w3);
      cf t0=cadd(z0,z2), t1=csub(z0,z2), t2=cadd(z1,z3), t3=csub(z1,z3);
      AT(base)      = cadd(t0,t2);
      AT(base+Ls)   = make_float2(t1.x - t3.y, t1.y + t3.x);
      AT(base+2*Ls) = csub(t0,t2);
      AT(base+3*Ls) = make_float2(t1.x + t3.y, t1.y - t3.x);
    }
  }
}

template<int N, int L, bool INV>
__device__ __forceinline__ void stage_r5(cf* __restrict__ s, const cf* __restrict__ tw, int tid, int nt){
  constexpr int Ls = L/5, nbf = N/5, tws = 16000/L;
  const float C1 = 0.30901699437494742f, S1c = 0.95105651629515357f;
  const float C2 = -0.80901699437494745f, S2c = 0.58778525229247314f;
  for (int q = tid; q < nbf; q += nt){
    int blk = q / Ls, j = q - blk*Ls;
    int base = blk*L + j;
    cf w1 = tw[tws*j]; if (INV) w1.y = -w1.y;
    cf w2 = cmul(w1,w1), w3 = cmul(w2,w1), w4 = cmul(w2,w2);
    if (!INV){
      cf y0=AT(base), y1=AT(base+Ls), y2=AT(base+2*Ls), y3=AT(base+3*Ls), y4=AT(base+4*Ls);
      cf t1=cadd(y1,y4), t2=csub(y1,y4), t3=cadd(y2,y3), t4=csub(y2,y3);
      cf z0 = cadd(y0, cadd(t1,t3));
      cf m1 = make_float2(y0.x + C1*t1.x + C2*t3.x, y0.y + C1*t1.y + C2*t3.y);
      cf m2 = make_float2(y0.x + C2*t1.x + C1*t3.x, y0.y + C2*t1.y + C1*t3.y);
      cf wa = make_float2(S1c*t2.x + S2c*t4.x, S1c*t2.y + S2c*t4.y);
      cf wb = make_float2(S2c*t2.x - S1c*t4.x, S2c*t2.y - S1c*t4.y);
      cf o1 = make_float2(m1.x + wa.y, m1.y - wa.x);
      cf o4 = make_float2(m1.x - wa.y, m1.y + wa.x);
      cf o2 = make_float2(m2.x + wb.y, m2.y - wb.x);
      cf o3 = make_float2(m2.x - wb.y, m2.y + wb.x);
      AT(base) = z0;
      AT(base+Ls)   = cmul(o1,w1);
      AT(base+2*Ls) = cmul(o2,w2);
      AT(base+3*Ls) = cmul(o3,w3);
      AT(base+4*Ls) = cmul(o4,w4);
    } else {
      cf z0=AT(base);
      cf z1=cmul(AT(base+Ls),   w1);
      cf z2=cmul(AT(base+2*Ls), w2);
      cf z3=cmul(AT(base+3*Ls), w3);
      cf z4=cmul(AT(base+4*Ls), w4);
      cf t1=cadd(z1,z4), t2=csub(z1,z4), t3=cadd(z2,z3), t4=csub(z2,z3);
      cf y0 = cadd(z0, cadd(t1,t3));
      cf m1 = make_float2(z0.x + C1*t1.x + C2*t3.x, z0.y + C1*t1.y + C2*t3.y);
      cf m2 = make_float2(z0.x + C2*t1.x + C1*t3.x, z0.y + C2*t1.y + C1*t3.y);
      cf wa = make_float2(S1c*t2.x + S2c*t4.x, S1c*t2.y + S2c*t4.y);
      cf wb = make_float2(S2c*t2.x - S1c*t4.x, S2c*t2.y - S1c*t4.y);
      AT(base)      = y0;
      AT(base+Ls)   = make_float2(m1.x - wa.y, m1.y + wa.x);
      AT(base+2*Ls) = make_float2(m2.x - wb.y, m2.y + wb.x);
      AT(base+3*Ls) = make_float2(m2.x + wb.y, m2.y - wb.x);
      AT(base+4*Ls) = make_float2(m1.x + wa.y, m1.y - wa.x);
    }
  }
}

// radix-8 stage (validated both directions in R17)
template<int N, int L, bool INV>
__device__ __forceinline__ void stage_r8(cf* __restrict__ s, const cf* __restrict__ tw, int tid, int nt){
  constexpr int Ls = L/8, nbf = N/8, tws = 16000/L;
  const float RC = 0.70710678118654752f;
  for (int q = tid; q < nbf; q += nt){
    int blk = q / Ls, j = q - blk*Ls;
    int base = blk*L + j;
    cf w1 = tw[tws*j]; if (INV) w1.y = -w1.y;
    cf w2 = cmul(w1,w1), w3 = cmul(w2,w1), w4 = cmul(w2,w2);
    cf w5 = cmul(w4,w1), w6 = cmul(w3,w3), w7 = cmul(w4,w3);
    if (!INV){
      cf y0=AT(base), y1=AT(base+Ls), y2=AT(base+2*Ls), y3=AT(base+3*Ls);
      cf y4=AT(base+4*Ls), y5=AT(base+5*Ls), y6=AT(base+6*Ls), y7=AT(base+7*Ls);
      cf b0=cadd(y0,y4), b1=csub(y0,y4);
      cf b2=cadd(y2,y6), b3=csub(y2,y6);
      cf b4=cadd(y1,y5), b5=csub(y1,y5);
      cf b6=cadd(y3,y7), b7=csub(y3,y7);
      cf r3 = make_float2(b3.y, -b3.x);
      cf r7 = make_float2(b7.y, -b7.x);
      cf c0=cadd(b0,b2), c1=csub(b0,b2);
      cf c2=cadd(b1,r3), c3=csub(b1,r3);
      cf c4=cadd(b4,b6), c5=csub(b4,b6);
      cf c6=cadd(b5,r7), c7=csub(b5,r7);
      cf r5 = make_float2(c5.y, -c5.x);
      cf wc6 = make_float2(RC*(c6.x + c6.y), RC*(c6.y - c6.x));
      cf wc7 = make_float2(RC*(c7.y - c7.x), RC*(-c7.y - c7.x));
      AT(base)      = cadd(c0,c4);
      AT(base+Ls)   = cmul(cadd(c2,wc6), w1);
      AT(base+2*Ls) = cmul(cadd(c1,r5),  w2);
      AT(base+3*Ls) = cmul(cadd(c3,wc7), w3);
      AT(base+4*Ls) = cmul(csub(c0,c4),  w4);
      AT(base+5*Ls) = cmul(csub(c2,wc6), w5);
      AT(base+6*Ls) = cmul(csub(c1,r5),  w6);
      AT(base+7*Ls) = cmul(csub(c3,wc7), w7);
    } else {
      cf z0=AT(base);
      cf z1=cmul(AT(base+Ls),   w1);
      cf z2=cmul(AT(base+2*Ls), w2);
      cf z3=cmul(AT(base+3*Ls), w3);
      cf z4=cmul(AT(base+4*Ls), w4);
      cf z5=cmul(AT(base+5*Ls), w5);
      cf z6=cmul(AT(base+6*Ls), w6);
      cf z7=cmul(AT(base+7*Ls), w7);
      cf b0=cadd(z0,z4), b1=csub(z0,z4);
      cf b2=cadd(z2,z6), b3=csub(z2,z6);
      cf b4=cadd(z1,z5), b5=csub(z1,z5);
      cf b6=cadd(z3,z7), b7=csub(z3,z7);
      cf r3 = make_float2(-b3.y, b3.x);
      cf r7 = make_float2(-b7.y, b7.x);
      cf c0=cadd(b0,b2), c1=csub(b0,b2);
      cf c2=cadd(b1,r3), c3=csub(b1,r3);
      cf c4=cadd(b4,b6), c5=csub(b4,b6);
      cf c6=cadd(b5,r7), c7=csub(b5,r7);
      cf r5 = make_float2(-c5.y, c5.x);
      cf wc6 = make_float2(RC*(c6.x - c6.y), RC*(c6.x + c6.y));
      cf wc7 = make_float2(RC*(-c7.x - c7.y), RC*(c7.x - c7.y));
      AT(base)      = cadd(c0,c4);
      AT(base+Ls)   = cadd(c2,wc6);
      AT(base+2*Ls) = cadd(c1,r5);
      AT(base+3*Ls) = cadd(c3,wc7);
      AT(base+4*Ls) = csub(c0,c4);
      AT(base+5*Ls) = csub(c2,wc6);
      AT(base+6*Ls) = csub(c1,r5);
      AT(base+7*Ls) = csub(c3,wc7);
    }
  }
}

// fused radix-16 final stage: EXACTLY r4@L16 (tw[1000j] twiddles) then r4@L4
// (twiddle-free, tw[0]=1) with the intermediate LDS round-trip+barrier elided.
// Output positions identical to the two-stage version -> pos maps unchanged.
template<int N, bool INV>
__device__ __forceinline__ void stage_r16(cf* __restrict__ s, const cf* __restrict__ tw, int tid, int nt){
  constexpr int ng = N/16;
  cf t1k = tw[1000], t2k = tw[2000], t3k = tw[3000];
  cf t4k = tw[4000], t6k = tw[6000], t9k = tw[9000];
  if (INV){
    t1k.y=-t1k.y; t2k.y=-t2k.y; t3k.y=-t3k.y;
    t4k.y=-t4k.y; t6k.y=-t6k.y; t9k.y=-t9k.y;
  }
  cf W1[3] = { t1k, t2k, t3k };   // W16^{j}   j=1..3
  cf W2[3] = { t2k, t4k, t6k };   // W16^{2j}
  cf W3[3] = { t3k, t6k, t9k };   // W16^{3j}
  for (int g = tid; g < ng; g += nt){
    int base = g*16;
    cf a[16];
    #pragma unroll
    for (int t = 0; t < 16; ++t) a[t] = AT(base+t);
    if (!INV){
      // phase 1: r4 over stride-4 (L=16) with W16^j output twiddles
      #pragma unroll
      for (int j = 0; j < 4; ++j){
        cf y0=a[j], y1=a[j+4], y2=a[j+8], y3=a[j+12];
        cf t0=cadd(y0,y2), t1=csub(y0,y2), t2=cadd(y1,y3), t3=csub(y1,y3);
        cf o1 = make_float2(t1.x+t3.y, t1.y-t3.x);
        cf o2 = csub(t0,t2);
        cf o3 = make_float2(t1.x-t3.y, t1.y+t3.x);
        a[j] = cadd(t0,t2);
        if (j==0){ a[j+4]=o1; a[j+8]=o2; a[j+12]=o3; }
        else { a[j+4]=cmul(o1,W1[j-1]); a[j+8]=cmul(o2,W2[j-1]); a[j+12]=cmul(o3,W3[j-1]); }
      }
      // phase 2: r4 over stride-1 (L=4), twiddle-free
      #pragma unroll
      for (int h = 0; h < 4; ++h){
        cf z0=a[4*h], z1=a[4*h+1], z2=a[4*h+2], z3=a[4*h+3];
        cf t0=cadd(z0,z2), t1=csub(z0,z2), t2=cadd(z1,z3), t3=csub(z1,z3);
        AT(base+4*h)   = cadd(t0,t2);
        AT(base+4*h+1) = make_float2(t1.x+t3.y, t1.y-t3.x);
        AT(base+4*h+2) = csub(t0,t2);
        AT(base+4*h+3) = make_float2(t1.x-t3.y, t1.y+t3.x);
      }
    } else {
      // phase 1: inv r4 over stride-1 (L=4), twiddle-free
      #pragma unroll
      for (int h = 0; h < 4; ++h){
        cf z0=a[4*h], z1=a[4*h+1], z2=a[4*h+2], z3=a[4*h+3];
        cf t0=cadd(z0,z2), t1=csub(z0,z2), t2=cadd(z1,z3), t3=csub(z1,z3);
        a[4*h]   = cadd(t0,t2);
        a[4*h+1] = make_float2(t1.x - t3.y, t1.y + t3.x);
        a[4*h+2] = csub(t0,t2);
        a[4*h+3] = make_float2(t1.x + t3.y, t1.y - t3.x);
      }
      // phase 2: inv r4 over stride-4 (L=16), conj twiddles on inputs
      #pragma unroll
      for (int j = 0; j < 4; ++j){
        cf z0=a[j];
        cf z1 = (j==0)? a[j+4]  : cmul(a[j+4],  W1[j-1]);
        cf z2 = (j==0)? a[j+8]  : cmul(a[j+8],  W2[j-1]);
        cf z3 = (j==0)? a[j+12] : cmul(a[j+12], W3[j-1]);
        cf t0=cadd(z0,z2), t1=csub(z0,z2), t2=cadd(z1,z3), t3=csub(z1,z3);
        AT(base+j)    = cadd(t0,t2);
        AT(base+j+4)  = make_float2(t1.x - t3.y, t1.y + t3.x);
        AT(base+j+8)  = csub(t0,t2);
        AT(base+j+12) = make_float2(t1.x + t3.y, t1.y - t3.x);
      }
    }
  }
}

// block-level transforms
// 16000 = 5^3 * 8*16  (5 stages; r16 fuses the old r4@16+r4@4 pair)
template<bool INV>
__device__ void fft16000(cf* s, const cf* tw, int tid, int nt){
  if (!INV){
    stage_r5<16000,16000,false>(s,tw,tid,nt); __syncthreads();
    stage_r5<16000, 3200,false>(s,tw,tid,nt); __syncthreads();
    stage_r5<16000,  640,false>(s,tw,tid,nt); __syncthreads();
    stage_r8<16000,  128,false>(s,tw,tid,nt); __syncthreads();
    stage_r16<16000,false>(s,tw,tid,nt); __syncthreads();
  } else {
    stage_r16<16000,true >(s,tw,tid,nt); __syncthreads();
    stage_r8<16000,  128,true >(s,tw,tid,nt); __syncthreads();
    stage_r5<16000,  640,true >(s,tw,tid,nt); __syncthreads();
    stage_r5<16000, 3200,true >(s,tw,tid,nt); __syncthreads();
    stage_r5<16000,16000,true >(s,tw,tid,nt); __syncthreads();
  }
}

// 2000 = 5^3 * 16 (4 stages via fused r16)
template<bool INV>
__device__ void fft2000(cf* s, const cf* tw, int tid, int nt){
  if (!INV){
    stage_r5<2000,2000,false>(s,tw,tid,nt); __syncthreads();
    stage_r5<2000, 400,false>(s,tw,tid,nt); __syncthreads();
    stage_r5<2000,  80,false>(s,tw,tid,nt); __syncthreads();
    stage_r16<2000,false>(s,tw,tid,nt); __syncthreads();
  } else {
    stage_r16<2000,true >(s,tw,tid,nt); __syncthreads();
    stage_r5<2000,  80,true >(s,tw,tid,nt); __syncthreads();
    stage_r5<2000, 400,true >(s,tw,tid,nt); __syncthreads();
    stage_r5<2000,2000,true >(s,tw,tid,nt); __syncthreads();
  }
}

// 8000 = 5^3 * 8*8 (5 stages)
__device__ void fft8000i(cf* s, const cf* tw, int tid, int nt){
  stage_r8<8000,   8,true>(s,tw,tid,nt); __syncthreads();
  stage_r8<8000,  64,true>(s,tw,tid,nt); __syncthreads();
  stage_r5<8000, 320,true>(s,tw,tid,nt); __syncthreads();
  stage_r5<8000,1600,true>(s,tw,tid,nt); __syncthreads();
  stage_r5<8000,8000,true>(s,tw,tid,nt); __syncthreads();
}
// 4000 = 5^3 * 8*4 (5 stages): inverse and forward
__device__ void fft4000i(cf* s, const cf* tw, int tid, int nt){
  stage_r4<4000,   4,true>(s,tw,tid,nt); __syncthreads();
  stage_r8<4000,  32,true>(s,tw,tid,nt); __syncthreads();
  stage_r5<4000, 160,true>(s,tw,tid,nt); __syncthreads();
  stage_r5<4000, 800,true>(s,tw,tid,nt); __syncthreads();
  stage_r5<4000,4000,true>(s,tw,tid,nt); __syncthreads();
}
__device__ void fft4000f(cf* s, const cf* tw, int tid, int nt){
  stage_r5<4000,4000,false>(s,tw,tid,nt); __syncthreads();
  stage_r5<4000, 800,false>(s,tw,tid,nt); __syncthreads();
  stage_r5<4000, 160,false>(s,tw,tid,nt); __syncthreads();
  stage_r8<4000,  32,false>(s,tw,tid,nt); __syncthreads();
  stage_r4<4000,   4,false>(s,tw,tid,nt); __syncthreads();
}
__device__ void fft500i(cf* s, const cf* tw, int tid, int nt){
  stage_r4<500,  4,true>(s,tw,tid,nt); __syncthreads();
  stage_r5<500, 20,true>(s,tw,tid,nt); __syncthreads();
  stage_r5<500,100,true>(s,tw,tid,nt); __syncthreads();
  stage_r5<500,500,true>(s,tw,tid,nt); __syncthreads();
}
// 1000 = 5^3 * 8 (4 stages)
__device__ void fft1000i(cf* s, const cf* tw, int tid, int nt){
  stage_r8<1000,   8,true>(s,tw,tid,nt); __syncthreads();
  stage_r5<1000,  40,true>(s,tw,tid,nt); __syncthreads();
  stage_r5<1000, 200,true>(s,tw,tid,nt); __syncthreads();
  stage_r5<1000,1000,true>(s,tw,tid,nt); __syncthreads();
}
__device__ __forceinline__ void fft250w(cf* s, const cf* tw, int lane){
  stage_r2<250,  2,true>(s,tw,lane,64); WFENCE;
  stage_r5<250, 10,true>(s,tw,lane,64); WFENCE;
  stage_r5<250, 50,true>(s,tw,lane,64); WFENCE;
  stage_r5<250,250,true>(s,tw,lane,64); WFENCE;
}
__device__ __forceinline__ void fft125w(cf* s, const cf* tw, int lane){
  stage_r5<125,  5,true>(s,tw,lane,64); WFENCE;
  stage_r5<125, 25,true>(s,tw,lane,64); WFENCE;
  stage_r5<125,125,true>(s,tw,lane,64); WFENCE;
}

// generic narrow-class transforms, WAVE selects fence type; radix-8/16 plans.
template<int M, bool INV, bool WAVE>
__device__ __forceinline__ void fftg(cf* s, const cf* tw, int tid, int nt){
  if constexpr (M==2000){
    if constexpr (INV){
      stage_r16<2000,true>(s,tw,tid,nt); SYf<WAVE>();
      stage_r5<2000,80,true>(s,tw,tid,nt); SYf<WAVE>();
      stage_r5<2000,400,true>(s,tw,tid,nt); SYf<WAVE>();
      stage_r5<2000,2000,true>(s,tw,tid,nt); SYf<WAVE>();
    } else {
      stage_r5<2000,2000,false>(s,tw,tid,nt); SYf<WAVE>();
      stage_r5<2000,400,false>(s,tw,tid,nt); SYf<WAVE>();
      stage_r5<2000,80,false>(s,tw,tid,nt); SYf<WAVE>();
      stage_r16<2000,false>(s,tw,tid,nt); SYf<WAVE>();
    }
  } else if constexpr (M==1600){  // {5,5,8,8}
    if constexpr (INV){
      stage_r8<1600,8,true>(s,tw,tid,nt); SYf<WAVE>();
      stage_r8<1600,64,true>(s,tw,tid,nt); SYf<WAVE>();
      stage_r5<1600,320,true>(s,tw,tid,nt); SYf<WAVE>();
      stage_r5<1600,1600,true>(s,tw,tid,nt); SYf<WAVE>();
    } else {
      stage_r5<1600,1600,false>(s,tw,tid,nt); SYf<WAVE>();
      stage_r5<1600,320,false>(s,tw,tid,nt); SYf<WAVE>();
      stage_r8<1600,64,false>(s,tw,tid,nt); SYf<WAVE>();
      stage_r8<1600,8,false>(s,tw,tid,nt); SYf<WAVE>();
    }
  } else if constexpr (M==640){   // {5,8,16}: 3 stages via fused r16
    if constexpr (INV){
      stage_r16<640,true>(s,tw,tid,nt); SYf<WAVE>();
      stage_r8<640,128,true>(s,tw,tid,nt); SYf<WAVE>();
      stage_r5<640,640,true>(s,tw,tid,nt); SYf<WAVE>();
    } else {
      stage_r5<640,640,false>(s,tw,tid,nt); SYf<WAVE>();
      stage_r8<640,128,false>(s,tw,tid,nt); SYf<WAVE>();
      stage_r16<640,false>(s,tw,tid,nt); SYf<WAVE>();
    }
  } else if constexpr (M==320){   // {5,8,8}
    if constexpr (INV){
      stage_r8<320,8,true>(s,tw,tid,nt); SYf<WAVE>();
      stage_r8<320,64,true>(s,tw,tid,nt); SYf<WAVE>();
      stage_r5<320,320,true>(s,tw,tid,nt); SYf<WAVE>();
    } else {
      stage_r5<320,320,false>(s,tw,tid,nt); SYf<WAVE>();
      stage_r8<320,64,false>(s,tw,tid,nt); SYf<WAVE>();
      stage_r8<320,8,false>(s,tw,tid,nt); SYf<WAVE>();
    }
  } else if constexpr (M==200){   // {5,5,8}
    if constexpr (INV){
      stage_r8<200,8,true>(s,tw,tid,nt); SYf<WAVE>();
      stage_r5<200,40,true>(s,tw,tid,nt); SYf<WAVE>();
      stage_r5<200,200,true>(s,tw,tid,nt); SYf<WAVE>();
    } else {
      stage_r5<200,200,false>(s,tw,tid,nt); SYf<WAVE>();
      stage_r5<200,40,false>(s,tw,tid,nt); SYf<WAVE>();
      stage_r8<200,8,false>(s,tw,tid,nt); SYf<WAVE>();
    }
  } else { // 160 = {5,8,4}
    if constexpr (INV){
      stage_r4<160,4,true>(s,tw,tid,nt); SYf<WAVE>();
      stage_r8<160,32,true>(s,tw,tid,nt); SYf<WAVE>();
      stage_r5<160,160,true>(s,tw,tid,nt); SYf<WAVE>();
    } else {
      stage_r5<160,160,false>(s,tw,tid,nt); SYf<WAVE>();
      stage_r8<160,32,false>(s,tw,tid,nt); SYf<WAVE>();
      stage_r4<160,4,false>(s,tw,tid,nt); SYf<WAVE>();
    }
  }
}

// digit-reversed positions per plan (UNCHANGED — r16 fusion preserves layout)
__device__ __forceinline__ int pos16000(int k){   // {5,5,5,8,4,4}
  int k0=k%5; k/=5; int k1=k%5; k/=5; int k2=k%5; k/=5;
  int k3=k&7; k>>=3; int k4=k&3; k>>=2;
  return k0*3200 + k1*640 + k2*128 + k3*16 + k4*4 + k;
}
__device__ __forceinline__ int pos8000(int k){    // {5,5,5,8,8}
  int k0=k%5; k/=5; int k1=k%5; k/=5; int k2=k%5; k/=5;
  int k3=k&7, k4=k>>3;
  return k0*1600 + k1*320 + k2*64 + k3*8 + k4;
}
__device__ __forceinline__ int pos4000(int k){    // {5,5,5,8,4}
  int k0=k%5; k/=5; int k1=k%5; k/=5; int k2=k%5; k/=5;
  int k3=k&7, k4=k>>3;
  return k0*800 + k1*160 + k2*32 + k3*4 + k4;
}
__device__ __forceinline__ int pos2000(int k){
  int k0=k%5; k/=5; int k1=k%5; k/=5; int k2=k%5; k/=5;
  int k3=k&3, k4=k>>2;
  return k0*400 + k1*80 + k2*16 + k3*4 + k4;
}
__device__ __forceinline__ int pos1600(int k){  // {5,5,8,8}
  int k0=k%5; k/=5; int k1=k%5; k/=5;
  int k2=k&7; k>>=3;
  return k0*320 + k1*64 + k2*8 + k;
}
__device__ __forceinline__ int pos1000(int k){  // {5,5,5,8}
  int k0=k%5; k/=5; int k1=k%5; k/=5; int k2=k%5; k/=5;
  return k0*200 + k1*40 + k2*8 + k;
}
__device__ __forceinline__ int pos640(int k){   // {5,8,4,4}
  int k0=k%5; k/=5;
  int k1=k&7; k>>=3; int k2=k&3; k>>=2;
  return k0*128 + k1*16 + k2*4 + k;
}
__device__ __forceinline__ int pos500(int k){
  int k0=k%5; k/=5; int k1=k%5; k/=5; int k2=k%5; k/=5;
  return k0*100 + k1*20 + k2*4 + k;
}
__device__ __forceinline__ int pos320(int k){   // {5,8,8}
  int k0=k%5; k/=5;
  int k1=k&7; k>>=3;
  return k0*64 + k1*8 + k;
}
__device__ __forceinline__ int pos250(int k){
  int k0=k%5; k/=5; int k1=k%5; k/=5; int k2=k%5; k/=5;
  return k0*50 + k1*10 + k2*2 + k;
}
__device__ __forceinline__ int pos125(int k){   // {5,5,5}
  int k0=k%5; k/=5; int k1=k%5; k/=5;
  return k0*25 + k1*5 + k;
}
__device__ __forceinline__ int pos200(int k){   // {5,5,8}
  int k0=k%5; k/=5; int k1=k%5; k/=5;
  return k0*40 + k1*8 + k;
}
__device__ __forceinline__ int pos160(int k){   // {5,8,4}
  int k0=k%5; k/=5;
  int k1=k&7; k>>=3;
  return k0*32 + k1*4 + k;
}

template<int M> __device__ __forceinline__ int posM(int k){
  if constexpr (M==16000) return pos16000(k);
  else if constexpr (M==8000) return pos8000(k);
  else if constexpr (M==4000) return pos4000(k);
  else return pos2000(k);
}
template<int M> __device__ __forceinline__ int posN(int k){
  if constexpr (M==2000) return pos2000(k);
  else if constexpr (M==1600) return pos1600(k);
  else if constexpr (M==640) return pos640(k);
  else if constexpr (M==320) return pos320(k);
  else if constexpr (M==200) return pos200(k);
  else return pos160(k);
}
template<int M> __device__ __forceinline__ void fftM_inv(cf* s, const cf* tw, int tid, int nt){
  if constexpr (M==16000) fft16000<true>(s,tw,tid,nt);
  else if constexpr (M==8000) fft8000i(s,tw,tid,nt);
  else if constexpr (M==4000) fft4000i(s,tw,tid,nt);
  else fft2000<true>(s,tw,tid,nt);
}

// ---------------- kernels ----------------

__global__ void k_tw(cf* __restrict__ tw){
  int j = blockIdx.x*blockDim.x + threadIdx.x;
  if (j < 16000){
    double a = -6.283185307179586476925286766559 * (double)j / 16000.0;
    tw[j] = make_float2((float)cos(a), (float)sin(a));
  }
}

__global__ void k_btab(const float* __restrict__ phi1, const float* __restrict__ phi2,
                       float* __restrict__ h1g, float* __restrict__ h2g){
  int i = blockIdx.x*blockDim.x + threadIdx.x;
  const double TWO_PI = 6.283185307179586476925286766559;
  if (i < 5201){
    int d = i - 2600;
    double a = 0.0;
    for (int k = 0; k < 64; ++k) a += (double)phi1[k]*cos(TWO_PI*(double)(k*d)/16000.0);
    h1g[i] = (float)(a/16000.0 - (double)phi1[0]/32000.0);
  } else if (i == 5201){
    h1g[5201] = phi1[0]*(1.f/32000.f);
  } else if (i < 5202 + 661){
    int j = i - 5202; int d = j - 330;
    double a = 0.0;
    for (int k = 0; k < 64; ++k) a += (double)phi2[k]*cos(TWO_PI*(double)(k*d)/2000.0);
    h2g[j] = (float)(a/2000.0 - (double)phi2[0]/4000.0);
  } else if (i == 5202 + 661){
    h2g[661] = phi2[0]*(1.f/4000.f);
  }
}

__global__ __launch_bounds__(1024) void k_classify(const int* __restrict__ pi2,
                                                   int* __restrict__ list5, int* __restrict__ list4){
  __shared__ int w5[16], w4[16];
  int p = threadIdx.x;
  for (int t = p; t < 493; t += 1024) list5[t] = 0;
  for (int t = p; t < 60;  t += 1024) list4[t] = 0;
  bool valid = p < 553;
  int j2 = valid ? pi2[p] : 99;
  bool f5 = valid && (j2 >= 5);
  bool f4 = valid && (j2 < 5);
  unsigned long long m5 = __ballot(f5);
  unsigned long long m4 = __ballot(f4);
  int lane = p & 63, wid = p >> 6;
  if (lane == 0){ w5[wid] = __popcll(m5); w4[wid] = __popcll(m4); }
  __syncthreads();
  if (valid){
    int b5 = 0, b4 = 0;
    for (int w = 0; w < wid; ++w){ b5 += w5[w]; b4 += w4[w]; }
    unsigned long long lm = (1ull << lane) - 1ull;
    if (f5) list5[b5 + __popcll(m5 & lm)] = p;
    if (f4) list4[b4 + __popcll(m4 & lm)] = p;
  }
}

// FFT of x, 4-way DIF split: block (b,r) computes X[4m+r] = FFT4000{y_r}[m],
// y_r[j] = (sum_q x[j+4000q] e^{-2pi i qr/4}) * tw[j*r].  NATURAL-order input.
__global__ __launch_bounds__(512) void k_fftx4(const float* __restrict__ x, cf* __restrict__ Xf,
                                               const cf* __restrict__ tw){
  extern __shared__ cf s[];
  int blk = blockIdx.x;
  int b = blk >> 2, r = blk & 3;
  int tid = threadIdx.x;
  const float* xb = x + (size_t)b*16000;
  for (int j = tid; j < 4000; j += 512){
    float x0 = xb[j], x1 = xb[j+4000], x2 = xb[j+8000], x3 = xb[j+12000];
    cf f;
    if (r == 0)      f = make_float2(x0 + x1 + x2 + x3, 0.f);
    else if (r == 1) f = make_float2(x0 - x2, x3 - x1);
    else if (r == 2) f = make_float2(x0 - x1 + x2 - x3, 0.f);
    else             f = make_float2(x0 - x2, x1 - x3);
    cf y = (r == 0) ? f : cmul(f, tw[j*r]);
    AT(j) = y;                           // natural order for forward DIF
  }
  __syncthreads();
  fft4000f(s, tw, tid, 512);
  cf* out = Xf + (size_t)b*16000 + r;
  for (int m = tid; m < 4000; m += 512) out[4*m] = AT(pos4000(m));
}

// Wide first-order classes (M=16000/8000/4000)
template<int M, int ST, int NF, int I0, int NT>
__global__ __launch_bounds__(NT) void kf(const cf* __restrict__ Xf, const float* __restrict__ psi1,
                                         const float* __restrict__ h1g, const cf* __restrict__ tw,
                                         cf* __restrict__ U1sf, float* __restrict__ S1){
  extern __shared__ cf s[];
  constexpr int NW = NT/64;
  int b = blockIdx.x / NF;
  int i = I0 + (blockIdx.x - b*NF);
  int tid = threadIdx.x, wid = tid>>6, lane = tid&63;
  double x1 = 0.45 * exp2((double)(-i) / 10.0);
  double kc = 16000.0 * x1;
  double sg = fmax(1600.0 * x1, 2.0);
  int k0 = max(0, (int)floor(kc - 6.5*sg));
  int k1 = min(16000, (int)ceil(kc + 6.5*sg) + 1);
  int W = k1 - k0;
  for (int n = tid; n < M; n += NT) s[n] = make_float2(0.f, 0.f);
  __syncthreads();
  const cf* X = Xf + (size_t)b*16000 + k0;
  const float* P = psi1 + (size_t)i*16000 + k0;
  for (int j = tid; j < W; j += NT){
    cf v = X[j]; float pf = P[j];
    int pp = posM<M>(j);
    AT(pp) = make_float2(v.x*pf, v.y*pf);
  }
  __syncthreads();
  fftM_inv<M>(s, tw, tid, NT);
  constexpr int R = (M + NT - 1)/NT;
  float mreg[R]; float tsum = 0.f;
  const float inv = 1.f/16000.f;
  #pragma unroll
  for (int r = 0; r < R; ++r){
    int n = tid + r*NT;
    if (n < M){ cf v = AT(n); mreg[r] = sqrtf(v.x*v.x + v.y*v.y)*inv; tsum += mreg[r]; }
    else mreg[r] = 0.f;
  }
  float* fl = (float*)s;
  float* part = (float*)(s + M);
  __syncthreads();
  #pragma unroll
  for (int r = 0; r < R; ++r){ int n = tid + r*NT; if (n < M) fl[n] = mreg[r]; }
  #pragma unroll
  for (int o = 32; o > 0; o >>= 1) tsum += __shfl_xor(tsum, o);
  if (lane == 0) part[wid] = tsum;
  __syncthreads();
  if (tid == 0){ float tt = 0.f; for (int w = 0; w < NW; ++w) tt += part[w]; part[NW] = tt; }
  __syncthreads();
  float stot = part[NW];
  float c1 = h1g[5201];
  for (int t = wid; t < 16; t += NW){
    int mlo = (1000*t - 2600)/ST;
    int mhi = (1000*t + 2600)/ST;
    float acc = 0.f;
    for (int m = mlo + lane; m <= mhi; m += 64){
      int mm = m; if (mm < 0) mm += M; else if (mm >= M) mm -= M;
      acc = fmaf(fl[mm], h1g[1000*t - m*ST + 2600], acc);
    }
    #pragma unroll
    for (int o = 32; o > 0; o >>= 1) acc += __shfl_xor(acc, o);
    if (lane == 0) S1[((size_t)b*120 + i)*16 + t] = (float)ST*(acc + c1*stot);
  }
  constexpr int K = 8/ST;
  float d0 = fl[tid*K];
  float d1 = 0.f;
  { int m2 = tid + 1024; if (m2 < 2000) d1 = fl[m2*K]; }
  __syncthreads();
  AT(tid) = make_float2(d0, 0.f);
  { int m2 = tid + 1024; if (m2 < 2000) AT(m2) = make_float2(d1, 0.f); }
  __syncthreads();
  fft2000<false>(s, tw, tid, NT);
  int B = devB(i);
  cf* out = U1sf + ((size_t)b*120 + i)*2000;
  for (int k = tid; k < B; k += NT) out[k] = AT(pos2000(k));
}

// Narrow first-order, block-level (M=2000/1600)
template<int M, int NF, int I0>
__global__ __launch_bounds__(256) void k_n2(const cf* __restrict__ Xf, const float* __restrict__ psi1,
                                            const float* __restrict__ phi1, const cf* __restrict__ tw,
                                            cf* __restrict__ U1sf, float* __restrict__ S1){
  extern __shared__ cf s[];
  int b = blockIdx.x / NF;
  int i = I0 + (blockIdx.x - b*NF);
  int tid = threadIdx.x, wid = tid>>6, lane = tid&63;
  double x1 = 0.45 * exp2((double)(-i)/10.0);
  double kc = 16000.0*x1, sg = fmax(1600.0*x1, 2.0);
  int k0 = max(0,(int)floor(kc-6.5*sg));
  int k1 = min(16000,(int)ceil(kc+6.5*sg)+1);
  int W = k1-k0;
  for (int n = tid; n < M; n += 256) s[n] = make_float2(0.f,0.f);
  __syncthreads();
  const cf* X = Xf + (size_t)b*16000 + k0;
  const float* P = psi1 + (size_t)i*16000 + k0;
  for (int j = tid; j < W; j += 256){
    cf v = X[j]; float pf = P[j];
    AT(posN<M>(j)) = make_float2(v.x*pf, v.y*pf);
  }
  __syncthreads();
  fftg<M,true,false>(s,tw,tid,256);
  for (int n = tid; n < M; n += 256){
    cf v = AT(n);
    AT(n) = make_float2(sqrtf(v.x*v.x+v.y*v.y)*(1.f/16000.f), 0.f);
  }
  __syncthreads();
  fftg<M,false,false>(s,tw,tid,256);
  {
    int k = lane;
    cf g = AT(posN<M>(k));
    float ph = phi1[k];
    float gx = g.x*ph, gy = g.y*ph;
    float* S1o = S1 + ((size_t)b*120+i)*16;
    for (int r = 0; r < 4; ++r){
      int t = wid + 4*r;
      cf e = tw[1000*((k*t)&15)];
      float val = gx*e.x + gy*e.y;
      #pragma unroll
      for (int o = 32; o > 0; o >>= 1) val += __shfl_xor(val, o);
      if (lane == 0) S1o[t] = val*(1.f/(float)M);
    }
  }
  int B = devB(i);
  const float sc = 2000.f/(float)M;
  cf* out = U1sf + ((size_t)b*120+i)*2000;
  for (int k = tid; k < B; k += 256){
    cf v = AT(posN<M>(k));
    out[k] = make_float2(v.x*sc, v.y*sc);
  }
}

// Narrow first-order, WAVE-LOCAL (M=640/320/200/160): zero barriers.
template<int M, int SPAD, int NF, int I0, int WPB>
__global__ __launch_bounds__(WPB*64) void k_nw2(const cf* __restrict__ Xf, const float* __restrict__ psi1,
                                                const float* __restrict__ phi1, const cf* __restrict__ tw,
                                                cf* __restrict__ U1sf, float* __restrict__ S1){
  extern __shared__ cf sh[];
  int wid = threadIdx.x >> 6, lane = threadIdx.x & 63;
  int q = blockIdx.x*WPB + wid;
  int filt = q >> 5, b = q & 31;
  int i = I0 + filt;
  cf* s = sh + wid*SPAD;
  double x1 = 0.45 * exp2((double)(-i)/10.0);
  double kc = 16000.0*x1, sg = fmax(1600.0*x1, 2.0);
  int k0 = max(0,(int)floor(kc-6.5*sg));
  int k1 = min(16000,(int)ceil(kc+6.5*sg)+1);
  int W = k1-k0;
  for (int n = lane; n < SPAD; n += 64) s[n] = make_float2(0.f,0.f);
  WFENCE;
  const cf* X = Xf + (size_t)b*16000 + k0;
  const float* P = psi1 + (size_t)i*16000 + k0;
  for (int j = lane; j < W; j += 64){
    cf v = X[j]; float pf = P[j];
    AT(posN<M>(j)) = make_float2(v.x*pf, v.y*pf);
  }
  WFENCE;
  fftg<M,true,true>(s,tw,lane,64);
  for (int n = lane; n < M; n += 64){
    cf v = AT(n);
    AT(n) = make_float2(sqrtf(v.x*v.x+v.y*v.y)*(1.f/16000.f), 0.f);
  }
  WFENCE;
  fftg<M,false,true>(s,tw,lane,64);
  {
    int k = lane;
    cf g = AT(posN<M>(k));
    float ph = phi1[k];
    float gx = g.x*ph, gy = g.y*ph;
    float* S1o = S1 + ((size_t)b*120+i)*16;
    for (int t = 0; t < 16; ++t){
      cf e = tw[1000*((k*t)&15)];
      float val = gx*e.x + gy*e.y;
      #pragma unroll
      for (int o = 32; o > 0; o >>= 1) val += __shfl_xor(val, o);
      if (lane == 0) S1o[t] = val*(1.f/(float)M);
    }
  }
  int B = devB(i);
  const float sc = 2000.f/(float)M;
  cf* out = U1sf + ((size_t)b*120+i)*2000;
  for (int k = lane; k < B; k += 64){
    cf v = AT(posN<M>(k));
    out[k] = make_float2(v.x*sc, v.y*sc);
  }
}

// Second order, j2>=5: one wave per (pair,batch).
__global__ __launch_bounds__(256) void k_sec5(const cf* __restrict__ U1sf, const float* __restrict__ psi2,
                                              const float* __restrict__ h2g, const cf* __restrict__ tw,
                                              const int* __restrict__ pi1, const int* __restrict__ pi2,
                                              const int* __restrict__ list5, float* __restrict__ S2){
  __shared__ cf sall[4*256];
  __shared__ float flall[4*256];
  int wid = threadIdx.x >> 6, lane = threadIdx.x & 63;
  int q = blockIdx.x*4 + wid;
  int p = list5[q >> 5];
  int b = q & 31;
  int i1 = pi1[p], j2 = pi2[p];
  cf* s = sall + wid*256;
  float* fl2 = flall + wid*256;
  int M2  = (j2 >= 6) ? 125 : 250;
  int s2l = (j2 >= 6) ? 4 : 3;
  double xc = exp2((double)(-j2));
  double kc = 900.0*xc, sg = fmax(180.0*xc, 2.0);
  int k0 = max(0, (int)floor(kc - 6.5*sg));
  int k1 = min(2000, (int)ceil(kc + 6.5*sg) + 1);
  int W = k1 - k0;
  for (int n = lane; n < 256; n += 64) s[n] = make_float2(0.f, 0.f);
  WFENCE;
  const cf* U = U1sf + (size_t)(b*120 + i1)*2000 + k0;
  const float* F = psi2 + j2*2000 + k0;
  for (int j = lane; j < W; j += 64){
    cf v = U[j]; float f = F[j];
    int pp = (M2 == 125) ? pos125(j) : pos250(j);
    AT(pp) = make_float2(v.x*f, v.y*f);
  }
  WFENCE;
  if (M2 == 125) fft125w(s, tw, lane); else fft250w(s, tw, lane);
  float tsum = 0.f;
  #pragma unroll
  for (int r = 0; r < 4; ++r){
    int n = lane + r*64;
    if (n < M2){
      cf v = AT(n);
      float mg = sqrtf(v.x*v.x + v.y*v.y)*(1.f/2000.f);
      fl2[n] = mg; tsum += mg;
    }
  }
  WFENCE;
  #pragma unroll
  for (int o = 32; o > 0; o >>= 1) tsum += __shfl_xor(tsum, o);
  float stot = tsum;
  float c2 = h2g[661];
  float scale = (float)(1 << s2l);
  float* S2o = S2 + (size_t)(b*553 + p)*16;
  int g16 = lane >> 4, li = lane & 15;
  for (int r = 0; r < 4; ++r){
    int t = g16*4 + r;
    int x0 = 125*t - 330, x1b = 125*t + 330;
    int mlo = (x0 + ((1<<s2l)-1)) >> s2l;
    int mhi = x1b >> s2l;
    float acc = 0.f;
    for (int m = mlo + li; m <= mhi; m += 16){
      int mm = m; if (mm < 0) mm += M2; else if (mm >= M2) mm -= M2;
      acc = fmaf(fl2[mm], h2g[125*t - (m << s2l) + 330], acc);
    }
    #pragma unroll
    for (int o = 8; o > 0; o >>= 1) acc += __shfl_xor(acc, o);
    if (li == 0) S2o[t] = scale*(acc + c2*stot);
  }
}

// Second order, j2<=4: block per (pair,batch).
__global__ __launch_bounds__(128) void k_secbig(const cf* __restrict__ U1sf, const float* __restrict__ psi2,
                                                const float* __restrict__ h2g, const cf* __restrict__ tw,
                                                const int* __restrict__ pi1, const int* __restrict__ pi2,
                                                const int* __restrict__ list4, float* __restrict__ S2){
  extern __shared__ cf s[];
  float* fl2 = (float*)(s + 2000);
  float* part = fl2 + 2000;
  int p = list4[blockIdx.x >> 5];
  int b = blockIdx.x & 31;
  int tid = threadIdx.x, wid = tid>>6, lane = tid&63;
  int i1 = pi1[p], j2 = pi2[p];
  int M2, s2l;
  if (j2 == 4){ M2 = 500;  s2l = 2; }
  else if (j2 == 3){ M2 = 1000; s2l = 1; }
  else { M2 = 2000; s2l = 0; }
  int ST2 = 1 << s2l;
  double xc = exp2((double)(-j2));
  double kc = 900.0*xc, sg = fmax(180.0*xc, 2.0);
  int k0 = max(0, (int)floor(kc - 6.5*sg));
  int k1 = min(2000, (int)ceil(kc + 6.5*sg) + 1);
  int W = k1 - k0;
  int M2r = (M2 + 15) & ~15;
  for (int n = tid; n < M2r; n += 128) s[n] = make_float2(0.f, 0.f);
  __syncthreads();
  const cf* U = U1sf + (size_t)(b*120 + i1)*2000 + k0;
  const float* F = psi2 + j2*2000 + k0;
  for (int j = tid; j < W; j += 128){
    cf v = U[j]; float f = F[j];
    int pp;
    if (M2 == 500) pp = pos500(j);
    else if (M2 == 1000) pp = pos1000(j);
    else pp = pos2000(j);
    AT(pp) = make_float2(v.x*f, v.y*f);
  }
  __syncthreads();
  if (M2 == 500) fft500i(s, tw, tid, 128);
  else if (M2 == 1000) fft1000i(s, tw, tid, 128);
  else fft2000<true>(s, tw, tid, 128);
  float tsum = 0.f;
  for (int n = tid; n < M2; n += 128){
    cf v = AT(n);
    float mg = sqrtf(v.x*v.x + v.y*v.y)*(1.f/2000.f);
    fl2[n] = mg; tsum += mg;
  }
  #pragma unroll
  for (int o = 32; o > 0; o >>= 1) tsum += __shfl_xor(tsum, o);
  if (lane == 0) part[wid] = tsum;
  __syncthreads();
  float stot = part[0] + part[1];
  float c2 = h2g[661];
  float* S2o = S2 + (size_t)(b*553 + p)*16;
  for (int r = 0; r < 8; ++r){
    int t = wid + (r<<1);
    int mlo = (125*t - 330 + ST2 - 1) >> s2l;
    int mhi = (125*t + 330) >> s2l;
    float acc = 0.f;
    for (int m = mlo + lane; m <= mhi; m += 64){
      int mm = m; if (mm < 0) mm += M2; else if (mm >= M2) mm -= M2;
      acc = fmaf(fl2[mm], h2g[125*t - m*ST2 + 330], acc);
    }
    #pragma unroll
    for (int o = 32; o > 0; o >>= 1) acc += __shfl_xor(acc, o);
    if (lane == 0) S2o[t] = (float)ST2*(acc + c2*stot);
  }
}

__global__ __launch_bounds__(64) void k_fbn(const float* __restrict__ S1, const float* __restrict__ S2,
                                            const float* __restrict__ g, const float* __restrict__ be,
                                            float* __restrict__ fn){
  int j = blockIdx.x;
  int b = threadIdx.x;
  float f = 0.f;
  if (b < 32){
    const float* src = (j < 120) ? (S1 + (b*120 + j)*16) : (S2 + (b*553 + (j-120))*16);
    float acc = 0.f;
    #pragma unroll
    for (int t = 0; t < 16; ++t) acc += logf(fabsf(src[t]) + 1e-6f);
    f = acc * (1.f/16.f);
  }
  float mu = f;
  #pragma unroll
  for (int o = 16; o > 0; o >>= 1) mu += __shfl_xor(mu, o);
  mu *= (1.f/32.f);
  float d = f - mu;
  float v = d*d;
  #pragma unroll
  for (int o = 16; o > 0; o >>= 1) v += __shfl_xor(v, o);
  v *= (1.f/32.f);
  float is = g[j] / sqrtf(v + 1e-5f);
  if (b < 32) fn[b*673 + j] = d*is + be[j];
}

__global__ __launch_bounds__(512) void k_mlp1(const float* __restrict__ fn,
                                              const float* __restrict__ W1, const float* __restrict__ b1,
                                              float* __restrict__ h1o){
  int task = blockIdx.x*8 + (threadIdx.x >> 6);
  int lane = threadIdx.x & 63;
  if (task >= 32*300) return;
  int b = task / 300, r = task - b*300;
  const float* f = fn + b*673;
  const float* w = W1 + r*673;
  float acc = 0.f;
  for (int k = lane; k < 673; k += 64) acc = fmaf(f[k], w[k], acc);
  #pragma unroll
  for (int o = 32; o > 0; o >>= 1) acc += __shfl_down(acc, o);
  if (lane == 0) h1o[b*300 + r] = fmaxf(acc + b1[r], 0.f);
}

__global__ __launch_bounds__(512) void k_mlp2(const float* __restrict__ h1,
                                              const float* __restrict__ W2, const float* __restrict__ b2,
                                              float* __restrict__ h2o){
  int task = blockIdx.x*8 + (threadIdx.x >> 6);
  int lane = threadIdx.x & 63;
  if (task >= 32*90) return;
  int b = task / 90, r = task - b*90;
  const float* h = h1 + b*300;
  const float* w = W2 + r*300;
  float acc = 0.f;
  for (int k = lane; k < 300; k += 64) acc = fmaf(h[k], w[k], acc);
  #pragma unroll
  for (int o = 32; o > 0; o >>= 1) acc += __shfl_down(acc, o);
  if (lane == 0) h2o[b*90 + r] = fmaxf(acc + b2[r], 0.f);
}

__global__ __launch_bounds__(256) void k_mlp3(const float* __restrict__ h2,
                                              const float* __restrict__ W3, const float* __restrict__ b3,
                                              float* __restrict__ out){
  __shared__ float lg[35];
  int b = blockIdx.x;
  int tid = threadIdx.x, wid = tid >> 6, lane = tid & 63;
  for (int r = wid; r < 35; r += 4){
    float acc = 0.f;
    for (int k = lane; k < 90; k += 64) acc = fmaf(h2[b*90 + k], W3[r*90 + k], acc);
    #pragma unroll
    for (int o = 32; o > 0; o >>= 1) acc += __shfl_down(acc, o);
    if (lane == 0) lg[r] = acc + b3[r];
  }
  __syncthreads();
  if (tid < 64){
    float v = (tid < 35) ? lg[tid] : -1e30f;
    float mx = v;
    #pragma unroll
    for (int o = 32; o > 0; o >>= 1) mx = fmaxf(mx, __shfl_xor(mx, o));
    float e = (tid < 35) ? expf(v - mx) : 0.f;
    float se = e;
    #pragma unroll
    for (int o = 32; o > 0; o >>= 1) se += __shfl_xor(se, o);
    if (tid < 35) out[b*35 + tid] = v - mx - logf(se);
  }
}

// ---------------- host ----------------

extern "C" void kernel_launch(void* const* d_in, const int* in_sizes, int n_in,
                              void* d_out, int out_size, void* d_ws, size_t ws_size,
                              hipStream_t stream){
  const float* x     = (const float*)d_in[0];
  const float* psi1  = (const float*)d_in[1];
  const float* phi1  = (const float*)d_in[2];
  const float* psi2  = (const float*)d_in[3];
  const float* phi2  = (const float*)d_in[4];
  const float* gamma = (const float*)d_in[5];
  const float* beta  = (const float*)d_in[6];
  const float* W1    = (const float*)d_in[7];
  const float* b1    = (const float*)d_in[8];
  const float* W2    = (const float*)d_in[9];
  const float* b2    = (const float*)d_in[10];
  const float* W3    = (const float*)d_in[11];
  const float* b3    = (const float*)d_in[12];
  const int*   pi1   = (const int*)d_in[13];
  const int*   pi2   = (const int*)d_in[14];

  char* ws = (char*)d_ws;
  constexpr size_t o_tw = 0;
  constexpr size_t o_Xf = o_tw + (size_t)16000*sizeof(cf);
  constexpr size_t o_U  = o_Xf + (size_t)32*16000*sizeof(cf);
  constexpr size_t o_S1 = o_U  + (size_t)3840*2000*sizeof(cf);
  constexpr size_t o_S2 = o_S1 + (size_t)3840*16*sizeof(float);
  constexpr size_t o_l5 = o_S2 + (size_t)17696*16*sizeof(float);
  constexpr size_t o_l4 = o_l5 + (size_t)512*sizeof(int);
  constexpr size_t o_fn = o_l4 + (size_t)64*sizeof(int);
  constexpr size_t o_h1 = o_fn + (size_t)32*673*sizeof(float);
  constexpr size_t o_h2 = o_h1 + (size_t)5202*sizeof(float);
  constexpr size_t o_m1 = o_h2 + (size_t)662*sizeof(float);
  constexpr size_t o_m2 = o_m1 + (size_t)32*300*sizeof(float);

  cf*    tw    = (cf*)(ws + o_tw);
  cf*    Xf    = (cf*)(ws + o_Xf);
  cf*    U1sf  = (cf*)(ws + o_U);
  float* S1b   = (float*)(ws + o_S1);
  float* S2b   = (float*)(ws + o_S2);
  int*   list5 = (int*)(ws + o_l5);
  int*   list4 = (int*)(ws + o_l4);
  float* fnbuf = (float*)(ws + o_fn);
  float* h1g   = (float*)(ws + o_h1);
  float* h2g   = (float*)(ws + o_h2);
  float* m1buf = (float*)(ws + o_m1);
  float* m2buf = (float*)(ws + o_m2);

  hipFuncSetAttribute((const void*)kf<16000,1,13, 0,1024>, hipFuncAttributeMaxDynamicSharedMemorySize, 131072);
  hipFuncSetAttribute((const void*)kf< 8000,2,10,13,1024>, hipFuncAttributeMaxDynamicSharedMemorySize, 131072);

  k_tw<<<63, 256, 0, stream>>>(tw);
  k_btab<<<23, 256, 0, stream>>>(phi1, phi2, h1g, h2g);
  k_classify<<<1, 1024, 0, stream>>>(pi2, list5, list4);
  k_fftx4<<<128, 512, 4000*8, stream>>>(x, Xf, tw);
  kf<16000,1,13, 0,1024><<<32*13, 1024, 16000*8 + 17*4, stream>>>(Xf, psi1, h1g, tw, U1sf, S1b);
  kf< 8000,2,10,13,1024><<<32*10, 1024,  8000*8 + 17*4, stream>>>(Xf, psi1, h1g, tw, U1sf, S1b);
  kf< 4000,4,10,23,1024><<<32*10, 1024,  4000*8 + 17*4, stream>>>(Xf, psi1, h1g, tw, U1sf, S1b);
  k_n2<2000,10,33><<<32*10, 256, 2000*8, stream>>>(Xf, psi1, phi1, tw, U1sf, S1b);
  k_n2<1600,10,43><<<32*10, 256, 1600*8, stream>>>(Xf, psi1, phi1, tw, U1sf, S1b);
  k_nw2<640,640,10,53,4><<< 80, 256, 4*640*8, stream>>>(Xf, psi1, phi1, tw, U1sf, S1b);
  k_nw2<320,320,10,63,8><<< 40, 512, 8*320*8, stream>>>(Xf, psi1, phi1, tw, U1sf, S1b);
  k_nw2<200,208,10,73,8><<< 40, 512, 8*208*8, stream>>>(Xf, psi1, phi1, tw, U1sf, S1b);
  k_nw2<160,160,37,83,8><<<148, 512, 8*160*8, stream>>>(Xf, psi1, phi1, tw, U1sf, S1b);
  k_sec5<<<(493*32)/4, 256, 0, stream>>>(U1sf, psi2, h2g, tw, pi1, pi2, list5, S2b);
  k_secbig<<<60*32, 128, 2000*8 + 2000*4 + 4*4, stream>>>(U1sf, psi2, h2g, tw, pi1, pi2, list4, S2b);
  k_fbn<<<673, 64, 0, stream>>>(S1b, S2b, gamma, beta, fnbuf);
  k_mlp1<<<1200, 512, 0, stream>>>(fnbuf, W1, b1, m1buf);
  k_mlp2<<<360, 512, 0, stream>>>(m1buf, W2, b2, m2buf);
  k_mlp3<<<32, 256, 0, stream>>>(m2buf, W3, b3, (float*)d_out);
}

// Round 22
// 331.081 us; speedup vs baseline: 1.0338x; 1.0338x over previous
//
#include <hip/hip_runtime.h>
#include <math.h>

typedef float2 cf;

__device__ __forceinline__ cf cadd(cf a, cf b){ return make_float2(a.x+b.x, a.y+b.y); }
__device__ __forceinline__ cf csub(cf a, cf b){ return make_float2(a.x-b.x, a.y-b.y); }
__device__ __forceinline__ cf cmul(cf a, cf b){ return make_float2(a.x*b.x - a.y*b.y, a.x*b.y + a.y*b.x); }

__device__ __forceinline__ int SW(int i){ return i ^ ((i>>4)&15); }
#define AT(x) s[SW(x)]
#define WFENCE asm volatile("" ::: "memory")

template<bool WAVE> __device__ __forceinline__ void SYf(){
  if constexpr (WAVE) { WFENCE; } else __syncthreads();
}

// bins of U1sf needed downstream for first-order filter i
__device__ __forceinline__ int devB(int i){
  int jm = i/10 + 2;
  double kc = 900.0*exp2((double)(-jm));
  double sg = fmax(180.0*exp2((double)(-jm)), 2.0);
  return min(2000, (int)ceil(kc + 6.5*sg) + 1);
}

// ---------------- mixed-radix FFT stages (DIF fwd / DIT inv) -------------
template<int N, int L, bool INV>
__device__ __forceinline__ void stage_r2(cf* __restrict__ s, const cf* __restrict__ tw, int tid, int nt){
  constexpr int Ls = L/2, nbf = N/2, tws = 16000/L;
  for (int q = tid; q < nbf; q += nt){
    int blk = q / Ls, j = q - blk*Ls;
    int base = blk*L + j;
    cf w1 = tw[tws*j]; if (INV) w1.y = -w1.y;
    if (!INV){
      cf a = AT(base), b = AT(base+Ls);
      AT(base) = cadd(a,b);
      AT(base+Ls) = cmul(csub(a,b), w1);
    } else {
      cf a = AT(base), b = cmul(AT(base+Ls), w1);
      AT(base) = cadd(a,b);
      AT(base+Ls) = csub(a,b);
    }
  }
}

template<int N, int L, bool INV>
__device__ __forceinline__ void stage_r4(cf* __restrict__ s, const cf* __restrict__ tw, int tid, int nt){
  constexpr int Ls = L/4, nbf = N/4, tws = 16000/L;
  for (int q = tid; q < nbf; q += nt){
    int blk = q / Ls, j = q - blk*Ls;
    int base = blk*L + j;
    cf w1 = tw[tws*j]; if (INV) w1.y = -w1.y;
    cf w2 = cmul(w1,w1), w3 = cmul(w2,w1);
    if (!INV){
      cf y0=AT(base), y1=AT(base+Ls), y2=AT(base+2*Ls), y3=AT(base+3*Ls);
      cf t0=cadd(y0,y2), t1=csub(y0,y2), t2=cadd(y1,y3), t3=csub(y1,y3);
      AT(base)      = cadd(t0,t2);
      AT(base+Ls)   = cmul(make_float2(t1.x + t3.y, t1.y - t3.x), w1);
      AT(base+2*Ls) = cmul(csub(t0,t2), w2);
      AT(base+3*Ls) = cmul(make_float2(t1.x - t3.y, t1.y + t3.x), w3);
    } else {
      cf z0=AT(base);
      cf z1=cmul(AT(base+Ls),   w1);
      cf z2=cmul(AT(base+2*Ls), w2);
      cf z3=cmul(AT(base+3*Ls), w3);
      cf t0=cadd(z0,z2), t1=csub(z0,z2), t2=cadd(z1,z3), t3=csub(z1,z3);
      AT(base)      = cadd(t0,t2);
      AT(base+Ls)   = make_float2(t1.x - t3.y, t1.y + t3.x);
      AT(base+2*Ls) = csub(t0,t2);
      AT(base+3*Ls) = make_float2(t1.x + t3.y, t1.y - t3.x);
    }
  }
}

template<int N, int L, bool INV>
__device__ __forceinline__ void stage_r5(cf* __restrict__ s, const cf* __restrict__ tw, int tid, int nt){
  constexpr int Ls = L/5, nbf = N/5, tws = 16000/L;
  const float C1 = 0.30901699437494742f, S1c = 0.95105651629515357f;
  const float C2 = -0.80901699437494745f, S2c = 0.58778525229247314f;
  for (int q = tid; q < nbf; q += nt){
    int blk = q / Ls, j = q - blk*Ls;
    int base = blk*L + j;
    cf w1 = tw[tws*j]; if (INV) w1.y = -w1.y;
    cf w2 = cmul(w1,w1), w3 = cmul(w2,w1), w4 = cmul(w2,w2);
    if (!INV){
      cf y0=AT(base), y1=AT(base+Ls), y2=AT(base+2*Ls), y3=AT(base+3*Ls), y4=AT(base+4*Ls);
      cf t1=cadd(y1,y4), t2=csub(y1,y4), t3=cadd(y2,y3), t4=csub(y2,y3);
      cf z0 = cadd(y0, cadd(t1,t3));
      cf m1 = make_float2(y0.x + C1*t1.x + C2*t3.x, y0.y + C1*t1.y + C2*t3.y);
      cf m2 = make_float2(y0.x + C2*t1.x + C1*t3.x, y0.y + C2*t1.y + C1*t3.y);
      cf wa = make_float2(S1c*t2.x + S2c*t4.x, S1c*t2.y + S2c*t4.y);
      cf wb = make_float2(S2c*t2.x - S1c*t4.x, S2c*t2.y - S1c*t4.y);
      cf o1 = make_float2(m1.x + wa.y, m1.y - wa.x);
      cf o4 = make_float2(m1.x - wa.y, m1.y + wa.x);
      cf o2 = make_float2(m2.x + wb.y, m2.y - wb.x);
      cf o3 = make_float2(m2.x - wb.y, m2.y + wb.x);
      AT(base) = z0;
      AT(base+Ls)   = cmul(o1,w1);
      AT(base+2*Ls) = cmul(o2,w2);
      AT(base+3*Ls) = cmul(o3,w3);
      AT(base+4*Ls) = cmul(o4,w4);
    } else {
      cf z0=AT(base);
      cf z1=cmul(AT(base+Ls),   w1);
      cf z2=cmul(AT(base+2*Ls), w2);
      cf z3=cmul(AT(base+3*Ls), w3);
      cf z4=cmul(AT(base+4*Ls), w4);
      cf t1=cadd(z1,z4), t2=csub(z1,z4), t3=cadd(z2,z3), t4=csub(z2,z3);
      cf y0 = cadd(z0, cadd(t1,t3));
      cf m1 = make_float2(z0.x + C1*t1.x + C2*t3.x, z0.y + C1*t1.y + C2*t3.y);
      cf m2 = make_float2(z0.x + C2*t1.x + C1*t3.x, z0.y + C2*t1.y + C1*t3.y);
      cf wa = make_float2(S1c*t2.x + S2c*t4.x, S1c*t2.y + S2c*t4.y);
      cf wb = make_float2(S2c*t2.x - S1c*t4.x, S2c*t2.y - S1c*t4.y);
      AT(base)      = y0;
      AT(base+Ls)   = make_float2(m1.x - wa.y, m1.y + wa.x);
      AT(base+2*Ls) = make_float2(m2.x - wb.y, m2.y + wb.x);
      AT(base+3*Ls) = make_float2(m2.x + wb.y, m2.y - wb.x);
      AT(base+4*Ls) = make_float2(m1.x + wa.y, m1.y - wa.x);
    }
  }
}

// radix-8 stage (validated both directions in R17)
template<int N, int L, bool INV>
__device__ __forceinline__ void stage_r8(cf* __restrict__ s, const cf* __restrict__ tw, int tid, int nt){
  constexpr int Ls = L/8, nbf = N/8, tws = 16000/L;
  const float RC = 0.70710678118654752f;
  for (int q = tid; q < nbf; q += nt){
    int blk = q / Ls, j = q - blk*Ls;
    int base = blk*L + j;
    cf w1 = tw[tws*j]; if (INV) w1.y = -w1.y;
    cf w2 = cmul(w1,w1), w3 = cmul(w2,w1), w4 = cmul(w2,w2);
    cf w5 = cmul(w4,w1), w6 = cmul(w3,w3), w7 = cmul(w4,w3);
    if (!INV){
      cf y0=AT(base), y1=AT(base+Ls), y2=AT(base+2*Ls), y3=AT(base+3*Ls);
      cf y4=AT(base+4*Ls), y5=AT(base+5*Ls), y6=AT(base+6*Ls), y7=AT(base+7*Ls);
      cf b0=cadd(y0,y4), b1=csub(y0,y4);
      cf b2=cadd(y2,y6), b3=csub(y2,y6);
      cf b4=cadd(y1,y5), b5=csub(y1,y5);
      cf b6=cadd(y3,y7), b7=csub(y3,y7);
      cf r3 = make_float2(b3.y, -b3.x);
      cf r7 = make_float2(b7.y, -b7.x);
      cf c0=cadd(b0,b2), c1=csub(b0,b2);
      cf c2=cadd(b1,r3), c3=csub(b1,r3);
      cf c4=cadd(b4,b6), c5=csub(b4,b6);
      cf c6=cadd(b5,r7), c7=csub(b5,r7);
      cf r5 = make_float2(c5.y, -c5.x);
      cf wc6 = make_float2(RC*(c6.x + c6.y), RC*(c6.y - c6.x));
      cf wc7 = make_float2(RC*(c7.y - c7.x), RC*(-c7.y - c7.x));
      AT(base)      = cadd(c0,c4);
      AT(base+Ls)   = cmul(cadd(c2,wc6), w1);
      AT(base+2*Ls) = cmul(cadd(c1,r5),  w2);
      AT(base+3*Ls) = cmul(cadd(c3,wc7), w3);
      AT(base+4*Ls) = cmul(csub(c0,c4),  w4);
      AT(base+5*Ls) = cmul(csub(c2,wc6), w5);
      AT(base+6*Ls) = cmul(csub(c1,r5),  w6);
      AT(base+7*Ls) = cmul(csub(c3,wc7), w7);
    } else {
      cf z0=AT(base);
      cf z1=cmul(AT(base+Ls),   w1);
      cf z2=cmul(AT(base+2*Ls), w2);
      cf z3=cmul(AT(base+3*Ls), w3);
      cf z4=cmul(AT(base+4*Ls), w4);
      cf z5=cmul(AT(base+5*Ls), w5);
      cf z6=cmul(AT(base+6*Ls), w6);
      cf z7=cmul(AT(base+7*Ls), w7);
      cf b0=cadd(z0,z4), b1=csub(z0,z4);
      cf b2=cadd(z2,z6), b3=csub(z2,z6);
      cf b4=cadd(z1,z5), b5=csub(z1,z5);
      cf b6=cadd(z3,z7), b7=csub(z3,z7);
      cf r3 = make_float2(-b3.y, b3.x);
      cf r7 = make_float2(-b7.y, b7.x);
      cf c0=cadd(b0,b2), c1=csub(b0,b2);
      cf c2=cadd(b1,r3), c3=csub(b1,r3);
      cf c4=cadd(b4,b6), c5=csub(b4,b6);
      cf c6=cadd(b5,r7), c7=csub(b5,r7);
      cf r5 = make_float2(-c5.y, c5.x);
      cf wc6 = make_float2(RC*(c6.x - c6.y), RC*(c6.x + c6.y));
      cf wc7 = make_float2(RC*(-c7.x - c7.y), RC*(c7.x - c7.y));
      AT(base)      = cadd(c0,c4);
      AT(base+Ls)   = cadd(c2,wc6);
      AT(base+2*Ls) = cadd(c1,r5);
      AT(base+3*Ls) = cadd(c3,wc7);
      AT(base+4*Ls) = csub(c0,c4);
      AT(base+5*Ls) = csub(c2,wc6);
      AT(base+6*Ls) = csub(c1,r5);
      AT(base+7*Ls) = csub(c3,wc7);
    }
  }
}

// fused radix-16 final stage — ONLY used where N/16 ≈ nt (fft16000 @1024).
// Exactly r4@L16 (tw[1000j]) then r4@L4 (twiddle-free); pos maps unchanged.
template<int N, bool INV>
__device__ __forceinline__ void stage_r16(cf* __restrict__ s, const cf* __restrict__ tw, int tid, int nt){
  constexpr int ng = N/16;
  cf t1k = tw[1000], t2k = tw[2000], t3k = tw[3000];
  cf t4k = tw[4000], t6k = tw[6000], t9k = tw[9000];
  if (INV){
    t1k.y=-t1k.y; t2k.y=-t2k.y; t3k.y=-t3k.y;
    t4k.y=-t4k.y; t6k.y=-t6k.y; t9k.y=-t9k.y;
  }
  cf W1[3] = { t1k, t2k, t3k };   // W16^{j}   j=1..3
  cf W2[3] = { t2k, t4k, t6k };   // W16^{2j}
  cf W3[3] = { t3k, t6k, t9k };   // W16^{3j}
  for (int g = tid; g < ng; g += nt){
    int base = g*16;
    cf a[16];
    #pragma unroll
    for (int t = 0; t < 16; ++t) a[t] = AT(base+t);
    if (!INV){
      #pragma unroll
      for (int j = 0; j < 4; ++j){
        cf y0=a[j], y1=a[j+4], y2=a[j+8], y3=a[j+12];
        cf t0=cadd(y0,y2), t1=csub(y0,y2), t2=cadd(y1,y3), t3=csub(y1,y3);
        cf o1 = make_float2(t1.x+t3.y, t1.y-t3.x);
        cf o2 = csub(t0,t2);
        cf o3 = make_float2(t1.x-t3.y, t1.y+t3.x);
        a[j] = cadd(t0,t2);
        if (j==0){ a[j+4]=o1; a[j+8]=o2; a[j+12]=o3; }
        else { a[j+4]=cmul(o1,W1[j-1]); a[j+8]=cmul(o2,W2[j-1]); a[j+12]=cmul(o3,W3[j-1]); }
      }
      #pragma unroll
      for (int h = 0; h < 4; ++h){
        cf z0=a[4*h], z1=a[4*h+1], z2=a[4*h+2], z3=a[4*h+3];
        cf t0=cadd(z0,z2), t1=csub(z0,z2), t2=cadd(z1,z3), t3=csub(z1,z3);
        AT(base+4*h)   = cadd(t0,t2);
        AT(base+4*h+1) = make_float2(t1.x+t3.y, t1.y-t3.x);
        AT(base+4*h+2) = csub(t0,t2);
        AT(base+4*h+3) = make_float2(t1.x-t3.y, t1.y+t3.x);
      }
    } else {
      #pragma unroll
      for (int h = 0; h < 4; ++h){
        cf z0=a[4*h], z1=a[4*h+1], z2=a[4*h+2], z3=a[4*h+3];
        cf t0=cadd(z0,z2), t1=csub(z0,z2), t2=cadd(z1,z3), t3=csub(z1,z3);
        a[4*h]   = cadd(t0,t2);
        a[4*h+1] = make_float2(t1.x - t3.y, t1.y + t3.x);
        a[4*h+2] = csub(t0,t2);
        a[4*h+3] = make_float2(t1.x + t3.y, t1.y - t3.x);
      }
      #pragma unroll
      for (int j = 0; j < 4; ++j){
        cf z0=a[j];
        cf z1 = (j==0)? a[j+4]  : cmul(a[j+4],  W1[j-1]);
        cf z2 = (j==0)? a[j+8]  : cmul(a[j+8],  W2[j-1]);
        cf z3 = (j==0)? a[j+12] : cmul(a[j+12], W3[j-1]);
        cf t0=cadd(z0,z2), t1=csub(z0,z2), t2=cadd(z1,z3), t3=csub(z1,z3);
        AT(base+j)    = cadd(t0,t2);
        AT(base+j+4)  = make_float2(t1.x - t3.y, t1.y + t3.x);
        AT(base+j+8)  = csub(t0,t2);
        AT(base+j+12) = make_float2(t1.x + t3.y, t1.y - t3.x);
      }
    }
  }
}

// block-level transforms
// 16000 = 5^3 * 8*16  (5 stages; r16 fused — 1000 groups @ NT=1024 is good util)
template<bool INV>
__device__ void fft16000(cf* s, const cf* tw, int tid, int nt){
  if (!INV){
    stage_r5<16000,16000,false>(s,tw,tid,nt); __syncthreads();
    stage_r5<16000, 3200,false>(s,tw,tid,nt); __syncthreads();
    stage_r5<16000,  640,false>(s,tw,tid,nt); __syncthreads();
    stage_r8<16000,  128,false>(s,tw,tid,nt); __syncthreads();
    stage_r16<16000,false>(s,tw,tid,nt); __syncthreads();
  } else {
    stage_r16<16000,true >(s,tw,tid,nt); __syncthreads();
    stage_r8<16000,  128,true >(s,tw,tid,nt); __syncthreads();
    stage_r5<16000,  640,true >(s,tw,tid,nt); __syncthreads();
    stage_r5<16000, 3200,true >(s,tw,tid,nt); __syncthreads();
    stage_r5<16000,16000,true >(s,tw,tid,nt); __syncthreads();
  }
}

// 2000 = 5^3 * 4*4 (5 stages — r16 would leave 7/8 threads idle at NT=1024)
template<bool INV>
__device__ void fft2000(cf* s, const cf* tw, int tid, int nt){
  if (!INV){
    stage_r5<2000,2000,false>(s,tw,tid,nt); __syncthreads();
    stage_r5<2000, 400,false>(s,tw,tid,nt); __syncthreads();
    stage_r5<2000,  80,false>(s,tw,tid,nt); __syncthreads();
    stage_r4<2000,  16,false>(s,tw,tid,nt); __syncthreads();
    stage_r4<2000,   4,false>(s,tw,tid,nt); __syncthreads();
  } else {
    stage_r4<2000,   4,true >(s,tw,tid,nt); __syncthreads();
    stage_r4<2000,  16,true >(s,tw,tid,nt); __syncthreads();
    stage_r5<2000,  80,true >(s,tw,tid,nt); __syncthreads();
    stage_r5<2000, 400,true >(s,tw,tid,nt); __syncthreads();
    stage_r5<2000,2000,true >(s,tw,tid,nt); __syncthreads();
  }
}

// 8000 = 5^3 * 8*8 (5 stages)
__device__ void fft8000i(cf* s, const cf* tw, int tid, int nt){
  stage_r8<8000,   8,true>(s,tw,tid,nt); __syncthreads();
  stage_r8<8000,  64,true>(s,tw,tid,nt); __syncthreads();
  stage_r5<8000, 320,true>(s,tw,tid,nt); __syncthreads();
  stage_r5<8000,1600,true>(s,tw,tid,nt); __syncthreads();
  stage_r5<8000,8000,true>(s,tw,tid,nt); __syncthreads();
}
// 4000 = 5^3 * 8*4 (5 stages): inverse and forward
__device__ void fft4000i(cf* s, const cf* tw, int tid, int nt){
  stage_r4<4000,   4,true>(s,tw,tid,nt); __syncthreads();
  stage_r8<4000,  32,true>(s,tw,tid,nt); __syncthreads();
  stage_r5<4000, 160,true>(s,tw,tid,nt); __syncthreads();
  stage_r5<4000, 800,true>(s,tw,tid,nt); __syncthreads();
  stage_r5<4000,4000,true>(s,tw,tid,nt); __syncthreads();
}
__device__ void fft4000f(cf* s, const cf* tw, int tid, int nt){
  stage_r5<4000,4000,false>(s,tw,tid,nt); __syncthreads();
  stage_r5<4000, 800,false>(s,tw,tid,nt); __syncthreads();
  stage_r5<4000, 160,false>(s,tw,tid,nt); __syncthreads();
  stage_r8<4000,  32,false>(s,tw,tid,nt); __syncthreads();
  stage_r4<4000,   4,false>(s,tw,tid,nt); __syncthreads();
}
__device__ void fft500i(cf* s, const cf* tw, int tid, int nt){
  stage_r4<500,  4,true>(s,tw,tid,nt); __syncthreads();
  stage_r5<500, 20,true>(s,tw,tid,nt); __syncthreads();
  stage_r5<500,100,true>(s,tw,tid,nt); __syncthreads();
  stage_r5<500,500,true>(s,tw,tid,nt); __syncthreads();
}
// 1000 = 5^3 * 8 (4 stages)
__device__ void fft1000i(cf* s, const cf* tw, int tid, int nt){
  stage_r8<1000,   8,true>(s,tw,tid,nt); __syncthreads();
  stage_r5<1000,  40,true>(s,tw,tid,nt); __syncthreads();
  stage_r5<1000, 200,true>(s,tw,tid,nt); __syncthreads();
  stage_r5<1000,1000,true>(s,tw,tid,nt); __syncthreads();
}
__device__ __forceinline__ void fft250w(cf* s, const cf* tw, int lane){
  stage_r2<250,  2,true>(s,tw,lane,64); WFENCE;
  stage_r5<250, 10,true>(s,tw,lane,64); WFENCE;
  stage_r5<250, 50,true>(s,tw,lane,64); WFENCE;
  stage_r5<250,250,true>(s,tw,lane,64); WFENCE;
}
__device__ __forceinline__ void fft125w(cf* s, const cf* tw, int lane){
  stage_r5<125,  5,true>(s,tw,lane,64); WFENCE;
  stage_r5<125, 25,true>(s,tw,lane,64); WFENCE;
  stage_r5<125,125,true>(s,tw,lane,64); WFENCE;
}

// generic narrow-class transforms, WAVE selects fence type; radix-8 plans.
template<int M, bool INV, bool WAVE>
__device__ __forceinline__ void fftg(cf* s, const cf* tw, int tid, int nt){
  if constexpr (M==2000){
    if constexpr (INV){
      stage_r4<2000,4,true>(s,tw,tid,nt); SYf<WAVE>();
      stage_r4<2000,16,true>(s,tw,tid,nt); SYf<WAVE>();
      stage_r5<2000,80,true>(s,tw,tid,nt); SYf<WAVE>();
      stage_r5<2000,400,true>(s,tw,tid,nt); SYf<WAVE>();
      stage_r5<2000,2000,true>(s,tw,tid,nt); SYf<WAVE>();
    } else {
      stage_r5<2000,2000,false>(s,tw,tid,nt); SYf<WAVE>();
      stage_r5<2000,400,false>(s,tw,tid,nt); SYf<WAVE>();
      stage_r5<2000,80,false>(s,tw,tid,nt); SYf<WAVE>();
      stage_r4<2000,16,false>(s,tw,tid,nt); SYf<WAVE>();
      stage_r4<2000,4,false>(s,tw,tid,nt); SYf<WAVE>();
    }
  } else if constexpr (M==1600){  // {5,5,8,8}
    if constexpr (INV){
      stage_r8<1600,8,true>(s,tw,tid,nt); SYf<WAVE>();
      stage_r8<1600,64,true>(s,tw,tid,nt); SYf<WAVE>();
      stage_r5<1600,320,true>(s,tw,tid,nt); SYf<WAVE>();
      stage_r5<1600,1600,true>(s,tw,tid,nt); SYf<WAVE>();
    } else {
      stage_r5<1600,1600,false>(s,tw,tid,nt); SYf<WAVE>();
      stage_r5<1600,320,false>(s,tw,tid,nt); SYf<WAVE>();
      stage_r8<1600,64,false>(s,tw,tid,nt); SYf<WAVE>();
      stage_r8<1600,8,false>(s,tw,tid,nt); SYf<WAVE>();
    }
  } else if constexpr (M==640){   // {5,8,4,4}
    if constexpr (INV){
      stage_r4<640,4,true>(s,tw,tid,nt); SYf<WAVE>();
      stage_r4<640,16,true>(s,tw,tid,nt); SYf<WAVE>();
      stage_r8<640,128,true>(s,tw,tid,nt); SYf<WAVE>();
      stage_r5<640,640,true>(s,tw,tid,nt); SYf<WAVE>();
    } else {
      stage_r5<640,640,false>(s,tw,tid,nt); SYf<WAVE>();
      stage_r8<640,128,false>(s,tw,tid,nt); SYf<WAVE>();
      stage_r4<640,16,false>(s,tw,tid,nt); SYf<WAVE>();
      stage_r4<640,4,false>(s,tw,tid,nt); SYf<WAVE>();
    }
  } else if constexpr (M==320){   // {5,8,8}
    if constexpr (INV){
      stage_r8<320,8,true>(s,tw,tid,nt); SYf<WAVE>();
      stage_r8<320,64,true>(s,tw,tid,nt); SYf<WAVE>();
      stage_r5<320,320,true>(s,tw,tid,nt); SYf<WAVE>();
    } else {
      stage_r5<320,320,false>(s,tw,tid,nt); SYf<WAVE>();
      stage_r8<320,64,false>(s,tw,tid,nt); SYf<WAVE>();
      stage_r8<320,8,false>(s,tw,tid,nt); SYf<WAVE>();
    }
  } else if constexpr (M==200){   // {5,5,8}
    if constexpr (INV){
      stage_r8<200,8,true>(s,tw,tid,nt); SYf<WAVE>();
      stage_r5<200,40,true>(s,tw,tid,nt); SYf<WAVE>();
      stage_r5<200,200,true>(s,tw,tid,nt); SYf<WAVE>();
    } else {
      stage_r5<200,200,false>(s,tw,tid,nt); SYf<WAVE>();
      stage_r5<200,40,false>(s,tw,tid,nt); SYf<WAVE>();
      stage_r8<200,8,false>(s,tw,tid,nt); SYf<WAVE>();
    }
  } else { // 160 = {5,8,4}
    if constexpr (INV){
      stage_r4<160,4,true>(s,tw,tid,nt); SYf<WAVE>();
      stage_r8<160,32,true>(s,tw,tid,nt); SYf<WAVE>();
      stage_r5<160,160,true>(s,tw,tid,nt); SYf<WAVE>();
    } else {
      stage_r5<160,160,false>(s,tw,tid,nt); SYf<WAVE>();
      stage_r8<160,32,false>(s,tw,tid,nt); SYf<WAVE>();
      stage_r4<160,4,false>(s,tw,tid,nt); SYf<WAVE>();
    }
  }
}

// digit-reversed positions per plan (descending-L digit convention)
__device__ __forceinline__ int pos16000(int k){   // {5,5,5,8,4,4}
  int k0=k%5; k/=5; int k1=k%5; k/=5; int k2=k%5; k/=5;
  int k3=k&7; k>>=3; int k4=k&3; k>>=2;
  return k0*3200 + k1*640 + k2*128 + k3*16 + k4*4 + k;
}
__device__ __forceinline__ int pos8000(int k){    // {5,5,5,8,8}
  int k0=k%5; k/=5; int k1=k%5; k/=5; int k2=k%5; k/=5;
  int k3=k&7, k4=k>>3;
  return k0*1600 + k1*320 + k2*64 + k3*8 + k4;
}
__device__ __forceinline__ int pos4000(int k){    // {5,5,5,8,4}
  int k0=k%5; k/=5; int k1=k%5; k/=5; int k2=k%5; k/=5;
  int k3=k&7, k4=k>>3;
  return k0*800 + k1*160 + k2*32 + k3*4 + k4;
}
__device__ __forceinline__ int pos2000(int k){
  int k0=k%5; k/=5; int k1=k%5; k/=5; int k2=k%5; k/=5;
  int k3=k&3, k4=k>>2;
  return k0*400 + k1*80 + k2*16 + k3*4 + k4;
}
__device__ __forceinline__ int pos1600(int k){  // {5,5,8,8}
  int k0=k%5; k/=5; int k1=k%5; k/=5;
  int k2=k&7; k>>=3;
  return k0*320 + k1*64 + k2*8 + k;
}
__device__ __forceinline__ int pos1000(int k){  // {5,5,5,8}
  int k0=k%5; k/=5; int k1=k%5; k/=5; int k2=k%5; k/=5;
  return k0*200 + k1*40 + k2*8 + k;
}
__device__ __forceinline__ int pos640(int k){   // {5,8,4,4}
  int k0=k%5; k/=5;
  int k1=k&7; k>>=3; int k2=k&3; k>>=2;
  return k0*128 + k1*16 + k2*4 + k;
}
__device__ __forceinline__ int pos500(int k){
  int k0=k%5; k/=5; int k1=k%5; k/=5; int k2=k%5; k/=5;
  return k0*100 + k1*20 + k2*4 + k;
}
__device__ __forceinline__ int pos320(int k){   // {5,8,8}
  int k0=k%5; k/=5;
  int k1=k&7; k>>=3;
  return k0*64 + k1*8 + k;
}
__device__ __forceinline__ int pos250(int k){
  int k0=k%5; k/=5; int k1=k%5; k/=5; int k2=k%5; k/=5;
  return k0*50 + k1*10 + k2*2 + k;
}
__device__ __forceinline__ int pos125(int k){   // {5,5,5}
  int k0=k%5; k/=5; int k1=k%5; k/=5;
  return k0*25 + k1*5 + k;
}
__device__ __forceinline__ int pos200(int k){   // {5,5,8}
  int k0=k%5; k/=5; int k1=k%5; k/=5;
  return k0*40 + k1*8 + k;
}
__device__ __forceinline__ int pos160(int k){   // {5,8,4}
  int k0=k%5; k/=5;
  int k1=k&7; k>>=3;
  return k0*32 + k1*4 + k;
}

template<int M> __device__ __forceinline__ int posM(int k){
  if constexpr (M==16000) return pos16000(k);
  else if constexpr (M==8000) return pos8000(k);
  else if constexpr (M==4000) return pos4000(k);
  else return pos2000(k);
}
template<int M> __device__ __forceinline__ int posN(int k){
  if constexpr (M==2000) return pos2000(k);
  else if constexpr (M==1600) return pos1600(k);
  else if constexpr (M==640) return pos640(k);
  else if constexpr (M==320) return pos320(k);
  else if constexpr (M==200) return pos200(k);
  else return pos160(k);
}
template<int M> __device__ __forceinline__ void fftM_inv(cf* s, const cf* tw, int tid, int nt){
  if constexpr (M==16000) fft16000<true>(s,tw,tid,nt);
  else if constexpr (M==8000) fft8000i(s,tw,tid,nt);
  else if constexpr (M==4000) fft4000i(s,tw,tid,nt);
  else fft2000<true>(s,tw,tid,nt);
}

// ---------------- kernels ----------------

__global__ void k_tw(cf* __restrict__ tw){
  int j = blockIdx.x*blockDim.x + threadIdx.x;
  if (j < 16000){
    double a = -6.283185307179586476925286766559 * (double)j / 16000.0;
    tw[j] = make_float2((float)cos(a), (float)sin(a));
  }
}

__global__ void k_btab(const float* __restrict__ phi1, const float* __restrict__ phi2,
                       float* __restrict__ h1g, float* __restrict__ h2g){
  int i = blockIdx.x*blockDim.x + threadIdx.x;
  const double TWO_PI = 6.283185307179586476925286766559;
  if (i < 5201){
    int d = i - 2600;
    double a = 0.0;
    for (int k = 0; k < 64; ++k) a += (double)phi1[k]*cos(TWO_PI*(double)(k*d)/16000.0);
    h1g[i] = (float)(a/16000.0 - (double)phi1[0]/32000.0);
  } else if (i == 5201){
    h1g[5201] = phi1[0]*(1.f/32000.f);
  } else if (i < 5202 + 661){
    int j = i - 5202; int d = j - 330;
    double a = 0.0;
    for (int k = 0; k < 64; ++k) a += (double)phi2[k]*cos(TWO_PI*(double)(k*d)/2000.0);
    h2g[j] = (float)(a/2000.0 - (double)phi2[0]/4000.0);
  } else if (i == 5202 + 661){
    h2g[661] = phi2[0]*(1.f/4000.f);
  }
}

__global__ __launch_bounds__(1024) void k_classify(const int* __restrict__ pi2,
                                                   int* __restrict__ list5, int* __restrict__ list4){
  __shared__ int w5[16], w4[16];
  int p = threadIdx.x;
  for (int t = p; t < 493; t += 1024) list5[t] = 0;
  for (int t = p; t < 60;  t += 1024) list4[t] = 0;
  bool valid = p < 553;
  int j2 = valid ? pi2[p] : 99;
  bool f5 = valid && (j2 >= 5);
  bool f4 = valid && (j2 < 5);
  unsigned long long m5 = __ballot(f5);
  unsigned long long m4 = __ballot(f4);
  int lane = p & 63, wid = p >> 6;
  if (lane == 0){ w5[wid] = __popcll(m5); w4[wid] = __popcll(m4); }
  __syncthreads();
  if (valid){
    int b5 = 0, b4 = 0;
    for (int w = 0; w < wid; ++w){ b5 += w5[w]; b4 += w4[w]; }
    unsigned long long lm = (1ull << lane) - 1ull;
    if (f5) list5[b5 + __popcll(m5 & lm)] = p;
    if (f4) list4[b4 + __popcll(m4 & lm)] = p;
  }
}

// FFT of x, 4-way DIF split: block (b,r) computes X[4m+r] = FFT4000{y_r}[m],
// y_r[j] = (sum_q x[j+4000q] e^{-2pi i qr/4}) * tw[j*r].  NATURAL-order input.
__global__ __launch_bounds__(512) void k_fftx4(const float* __restrict__ x, cf* __restrict__ Xf,
                                               const cf* __restrict__ tw){
  extern __shared__ cf s[];
  int blk = blockIdx.x;
  int b = blk >> 2, r = blk & 3;
  int tid = threadIdx.x;
  const float* xb = x + (size_t)b*16000;
  for (int j = tid; j < 4000; j += 512){
    float x0 = xb[j], x1 = xb[j+4000], x2 = xb[j+8000], x3 = xb[j+12000];
    cf f;
    if (r == 0)      f = make_float2(x0 + x1 + x2 + x3, 0.f);
    else if (r == 1) f = make_float2(x0 - x2, x3 - x1);
    else if (r == 2) f = make_float2(x0 - x1 + x2 - x3, 0.f);
    else             f = make_float2(x0 - x2, x1 - x3);
    cf y = (r == 0) ? f : cmul(f, tw[j*r]);
    AT(j) = y;                           // natural order for forward DIF
  }
  __syncthreads();
  fft4000f(s, tw, tid, 512);
  cf* out = Xf + (size_t)b*16000 + r;
  for (int m = tid; m < 4000; m += 512) out[4*m] = AT(pos4000(m));
}

// Wide first-order classes (M=16000/8000/4000)
template<int M, int ST, int NF, int I0, int NT>
__global__ __launch_bounds__(NT) void kf(const cf* __restrict__ Xf, const float* __restrict__ psi1,
                                         const float* __restrict__ h1g, const cf* __restrict__ tw,
                                         cf* __restrict__ U1sf, float* __restrict__ S1){
  extern __shared__ cf s[];
  constexpr int NW = NT/64;
  int b = blockIdx.x / NF;
  int i = I0 + (blockIdx.x - b*NF);
  int tid = threadIdx.x, wid = tid>>6, lane = tid&63;
  double x1 = 0.45 * exp2((double)(-i) / 10.0);
  double kc = 16000.0 * x1;
  double sg = fmax(1600.0 * x1, 2.0);
  int k0 = max(0, (int)floor(kc - 6.5*sg));
  int k1 = min(16000, (int)ceil(kc + 6.5*sg) + 1);
  int W = k1 - k0;
  for (int n = tid; n < M; n += NT) s[n] = make_float2(0.f, 0.f);
  __syncthreads();
  const cf* X = Xf + (size_t)b*16000 + k0;
  const float* P = psi1 + (size_t)i*16000 + k0;
  for (int j = tid; j < W; j += NT){
    cf v = X[j]; float pf = P[j];
    int pp = posM<M>(j);
    AT(pp) = make_float2(v.x*pf, v.y*pf);
  }
  __syncthreads();
  fftM_inv<M>(s, tw, tid, NT);
  constexpr int R = (M + NT - 1)/NT;
  float mreg[R]; float tsum = 0.f;
  const float inv = 1.f/16000.f;
  #pragma unroll
  for (int r = 0; r < R; ++r){
    int n = tid + r*NT;
    if (n < M){ cf v = AT(n); mreg[r] = sqrtf(v.x*v.x + v.y*v.y)*inv; tsum += mreg[r]; }
    else mreg[r] = 0.f;
  }
  float* fl = (float*)s;
  float* part = (float*)(s + M);
  __syncthreads();
  #pragma unroll
  for (int r = 0; r < R; ++r){ int n = tid + r*NT; if (n < M) fl[n] = mreg[r]; }
  #pragma unroll
  for (int o = 32; o > 0; o >>= 1) tsum += __shfl_xor(tsum, o);
  if (lane == 0) part[wid] = tsum;
  __syncthreads();
  if (tid == 0){ float tt = 0.f; for (int w = 0; w < NW; ++w) tt += part[w]; part[NW] = tt; }
  __syncthreads();
  float stot = part[NW];
  float c1 = h1g[5201];
  for (int t = wid; t < 16; t += NW){
    int mlo = (1000*t - 2600)/ST;
    int mhi = (1000*t + 2600)/ST;
    float acc = 0.f;
    for (int m = mlo + lane; m <= mhi; m += 64){
      int mm = m; if (mm < 0) mm += M; else if (mm >= M) mm -= M;
      acc = fmaf(fl[mm], h1g[1000*t - m*ST + 2600], acc);
    }
    #pragma unroll
    for (int o = 32; o > 0; o >>= 1) acc += __shfl_xor(acc, o);
    if (lane == 0) S1[((size_t)b*120 + i)*16 + t] = (float)ST*(acc + c1*stot);
  }
  constexpr int K = 8/ST;
  float d0 = fl[tid*K];
  float d1 = 0.f;
  { int m2 = tid + 1024; if (m2 < 2000) d1 = fl[m2*K]; }
  __syncthreads();
  AT(tid) = make_float2(d0, 0.f);
  { int m2 = tid + 1024; if (m2 < 2000) AT(m2) = make_float2(d1, 0.f); }
  __syncthreads();
  fft2000<false>(s, tw, tid, NT);
  int B = devB(i);
  cf* out = U1sf + ((size_t)b*120 + i)*2000;
  for (int k = tid; k < B; k += NT) out[k] = AT(pos2000(k));
}

// Narrow first-order, block-level (M=2000/1600)
template<int M, int NF, int I0>
__global__ __launch_bounds__(256) void k_n2(const cf* __restrict__ Xf, const float* __restrict__ psi1,
                                            const float* __restrict__ phi1, const cf* __restrict__ tw,
                                            cf* __restrict__ U1sf, float* __restrict__ S1){
  extern __shared__ cf s[];
  int b = blockIdx.x / NF;
  int i = I0 + (blockIdx.x - b*NF);
  int tid = threadIdx.x, wid = tid>>6, lane = tid&63;
  double x1 = 0.45 * exp2((double)(-i)/10.0);
  double kc = 16000.0*x1, sg = fmax(1600.0*x1, 2.0);
  int k0 = max(0,(int)floor(kc-6.5*sg));
  int k1 = min(16000,(int)ceil(kc+6.5*sg)+1);
  int W = k1-k0;
  for (int n = tid; n < M; n += 256) s[n] = make_float2(0.f,0.f);
  __syncthreads();
  const cf* X = Xf + (size_t)b*16000 + k0;
  const float* P = psi1 + (size_t)i*16000 + k0;
  for (int j = tid; j < W; j += 256){
    cf v = X[j]; float pf = P[j];
    AT(posN<M>(j)) = make_float2(v.x*pf, v.y*pf);
  }
  __syncthreads();
  fftg<M,true,false>(s,tw,tid,256);
  for (int n = tid; n < M; n += 256){
    cf v = AT(n);
    AT(n) = make_float2(sqrtf(v.x*v.x+v.y*v.y)*(1.f/16000.f), 0.f);
  }
  __syncthreads();
  fftg<M,false,false>(s,tw,tid,256);
  {
    int k = lane;
    cf g = AT(posN<M>(k));
    float ph = phi1[k];
    float gx = g.x*ph, gy = g.y*ph;
    float* S1o = S1 + ((size_t)b*120+i)*16;
    for (int r = 0; r < 4; ++r){
      int t = wid + 4*r;
      cf e = tw[1000*((k*t)&15)];
      float val = gx*e.x + gy*e.y;
      #pragma unroll
      for (int o = 32; o > 0; o >>= 1) val += __shfl_xor(val, o);
      if (lane == 0) S1o[t] = val*(1.f/(float)M);
    }
  }
  int B = devB(i);
  const float sc = 2000.f/(float)M;
  cf* out = U1sf + ((size_t)b*120+i)*2000;
  for (int k = tid; k < B; k += 256){
    cf v = AT(posN<M>(k));
    out[k] = make_float2(v.x*sc, v.y*sc);
  }
}

// Narrow first-order, WAVE-LOCAL (M=640/320/200/160): zero barriers.
template<int M, int SPAD, int NF, int I0, int WPB>
__global__ __launch_bounds__(WPB*64) void k_nw2(const cf* __restrict__ Xf, const float* __restrict__ psi1,
                                                const float* __restrict__ phi1, const cf* __restrict__ tw,
                                                cf* __restrict__ U1sf, float* __restrict__ S1){
  extern __shared__ cf sh[];
  int wid = threadIdx.x >> 6, lane = threadIdx.x & 63;
  int q = blockIdx.x*WPB + wid;
  int filt = q >> 5, b = q & 31;
  int i = I0 + filt;
  cf* s = sh + wid*SPAD;
  double x1 = 0.45 * exp2((double)(-i)/10.0);
  double kc = 16000.0*x1, sg = fmax(1600.0*x1, 2.0);
  int k0 = max(0,(int)floor(kc-6.5*sg));
  int k1 = min(16000,(int)ceil(kc+6.5*sg)+1);
  int W = k1-k0;
  for (int n = lane; n < SPAD; n += 64) s[n] = make_float2(0.f,0.f);
  WFENCE;
  const cf* X = Xf + (size_t)b*16000 + k0;
  const float* P = psi1 + (size_t)i*16000 + k0;
  for (int j = lane; j < W; j += 64){
    cf v = X[j]; float pf = P[j];
    AT(posN<M>(j)) = make_float2(v.x*pf, v.y*pf);
  }
  WFENCE;
  fftg<M,true,true>(s,tw,lane,64);
  for (int n = lane; n < M; n += 64){
    cf v = AT(n);
    AT(n) = make_float2(sqrtf(v.x*v.x+v.y*v.y)*(1.f/16000.f), 0.f);
  }
  WFENCE;
  fftg<M,false,true>(s,tw,lane,64);
  {
    int k = lane;
    cf g = AT(posN<M>(k));
    float ph = phi1[k];
    float gx = g.x*ph, gy = g.y*ph;
    float* S1o = S1 + ((size_t)b*120+i)*16;
    for (int t = 0; t < 16; ++t){
      cf e = tw[1000*((k*t)&15)];
      float val = gx*e.x + gy*e.y;
      #pragma unroll
      for (int o = 32; o > 0; o >>= 1) val += __shfl_xor(val, o);
      if (lane == 0) S1o[t] = val*(1.f/(float)M);
    }
  }
  int B = devB(i);
  const float sc = 2000.f/(float)M;
  cf* out = U1sf + ((size_t)b*120+i)*2000;
  for (int k = lane; k < B; k += 64){
    cf v = AT(posN<M>(k));
    out[k] = make_float2(v.x*sc, v.y*sc);
  }
}

// Second order, j2>=5: one wave per (pair,batch).
__global__ __launch_bounds__(256) void k_sec5(const cf* __restrict__ U1sf, const float* __restrict__ psi2,
                                              const float* __restrict__ h2g, const cf* __restrict__ tw,
                                              const int* __restrict__ pi1, const int* __restrict__ pi2,
                                              const int* __restrict__ list5, float* __restrict__ S2){
  __shared__ cf sall[4*256];
  __shared__ float flall[4*256];
  int wid = threadIdx.x >> 6, lane = threadIdx.x & 63;
  int q = blockIdx.x*4 + wid;
  int p = list5[q >> 5];
  int b = q & 31;
  int i1 = pi1[p], j2 = pi2[p];
  cf* s = sall + wid*256;
  float* fl2 = flall + wid*256;
  int M2  = (j2 >= 6) ? 125 : 250;
  int s2l = (j2 >= 6) ? 4 : 3;
  double xc = exp2((double)(-j2));
  double kc = 900.0*xc, sg = fmax(180.0*xc, 2.0);
  int k0 = max(0, (int)floor(kc - 6.5*sg));
  int k1 = min(2000, (int)ceil(kc + 6.5*sg) + 1);
  int W = k1 - k0;
  for (int n = lane; n < 256; n += 64) s[n] = make_float2(0.f, 0.f);
  WFENCE;
  const cf* U = U1sf + (size_t)(b*120 + i1)*2000 + k0;
  const float* F = psi2 + j2*2000 + k0;
  for (int j = lane; j < W; j += 64){
    cf v = U[j]; float f = F[j];
    int pp = (M2 == 125) ? pos125(j) : pos250(j);
    AT(pp) = make_float2(v.x*f, v.y*f);
  }
  WFENCE;
  if (M2 == 125) fft125w(s, tw, lane); else fft250w(s, tw, lane);
  float tsum = 0.f;
  #pragma unroll
  for (int r = 0; r < 4; ++r){
    int n = lane + r*64;
    if (n < M2){
      cf v = AT(n);
      float mg = sqrtf(v.x*v.x + v.y*v.y)*(1.f/2000.f);
      fl2[n] = mg; tsum += mg;
    }
  }
  WFENCE;
  #pragma unroll
  for (int o = 32; o > 0; o >>= 1) tsum += __shfl_xor(tsum, o);
  float stot = tsum;
  float c2 = h2g[661];
  float scale = (float)(1 << s2l);
  float* S2o = S2 + (size_t)(b*553 + p)*16;
  int g16 = lane >> 4, li = lane & 15;
  for (int r = 0; r < 4; ++r){
    int t = g16*4 + r;
    int x0 = 125*t - 330, x1b = 125*t + 330;
    int mlo = (x0 + ((1<<s2l)-1)) >> s2l;
    int mhi = x1b >> s2l;
    float acc = 0.f;
    for (int m = mlo + li; m <= mhi; m += 16){
      int mm = m; if (mm < 0) mm += M2; else if (mm >= M2) mm -= M2;
      acc = fmaf(fl2[mm], h2g[125*t - (m << s2l) + 330], acc);
    }
    #pragma unroll
    for (int o = 8; o > 0; o >>= 1) acc += __shfl_xor(acc, o);
    if (li == 0) S2o[t] = scale*(acc + c2*stot);
  }
}

// Second order, j2<=4: block per (pair,batch).
__global__ __launch_bounds__(128) void k_secbig(const cf* __restrict__ U1sf, const float* __restrict__ psi2,
                                                const float* __restrict__ h2g, const cf* __restrict__ tw,
                                                const int* __restrict__ pi1, const int* __restrict__ pi2,
                                                const int* __restrict__ list4, float* __restrict__ S2){
  extern __shared__ cf s[];
  float* fl2 = (float*)(s + 2000);
  float* part = fl2 + 2000;
  int p = list4[blockIdx.x >> 5];
  int b = blockIdx.x & 31;
  int tid = threadIdx.x, wid = tid>>6, lane = tid&63;
  int i1 = pi1[p], j2 = pi2[p];
  int M2, s2l;
  if (j2 == 4){ M2 = 500;  s2l = 2; }
  else if (j2 == 3){ M2 = 1000; s2l = 1; }
  else { M2 = 2000; s2l = 0; }
  int ST2 = 1 << s2l;
  double xc = exp2((double)(-j2));
  double kc = 900.0*xc, sg = fmax(180.0*xc, 2.0);
  int k0 = max(0, (int)floor(kc - 6.5*sg));
  int k1 = min(2000, (int)ceil(kc + 6.5*sg) + 1);
  int W = k1 - k0;
  int M2r = (M2 + 15) & ~15;
  for (int n = tid; n < M2r; n += 128) s[n] = make_float2(0.f, 0.f);
  __syncthreads();
  const cf* U = U1sf + (size_t)(b*120 + i1)*2000 + k0;
  const float* F = psi2 + j2*2000 + k0;
  for (int j = tid; j < W; j += 128){
    cf v = U[j]; float f = F[j];
    int pp;
    if (M2 == 500) pp = pos500(j);
    else if (M2 == 1000) pp = pos1000(j);
    else pp = pos2000(j);
    AT(pp) = make_float2(v.x*f, v.y*f);
  }
  __syncthreads();
  if (M2 == 500) fft500i(s, tw, tid, 128);
  else if (M2 == 1000) fft1000i(s, tw, tid, 128);
  else fft2000<true>(s, tw, tid, 128);
  float tsum = 0.f;
  for (int n = tid; n < M2; n += 128){
    cf v = AT(n);
    float mg = sqrtf(v.x*v.x + v.y*v.y)*(1.f/2000.f);
    fl2[n] = mg; tsum += mg;
  }
  #pragma unroll
  for (int o = 32; o > 0; o >>= 1) tsum += __shfl_xor(tsum, o);
  if (lane == 0) part[wid] = tsum;
  __syncthreads();
  float stot = part[0] + part[1];
  float c2 = h2g[661];
  float* S2o = S2 + (size_t)(b*553 + p)*16;
  for (int r = 0; r < 8; ++r){
    int t = wid + (r<<1);
    int mlo = (125*t - 330 + ST2 - 1) >> s2l;
    int mhi = (125*t + 330) >> s2l;
    float acc = 0.f;
    for (int m = mlo + lane; m <= mhi; m += 64){
      int mm = m; if (mm < 0) mm += M2; else if (mm >= M2) mm -= M2;
      acc = fmaf(fl2[mm], h2g[125*t - m*ST2 + 330], acc);
    }
    #pragma unroll
    for (int o = 32; o > 0; o >>= 1) acc += __shfl_xor(acc, o);
    if (lane == 0) S2o[t] = (float)ST2*(acc + c2*stot);
  }
}

__global__ __launch_bounds__(64) void k_fbn(const float* __restrict__ S1, const float* __restrict__ S2,
                                            const float* __restrict__ g, const float* __restrict__ be,
                                            float* __restrict__ fn){
  int j = blockIdx.x;
  int b = threadIdx.x;
  float f = 0.f;
  if (b < 32){
    const float* src = (j < 120) ? (S1 + (b*120 + j)*16) : (S2 + (b*553 + (j-120))*16);
    float acc = 0.f;
    #pragma unroll
    for (int t = 0; t < 16; ++t) acc += logf(fabsf(src[t]) + 1e-6f);
    f = acc * (1.f/16.f);
  }
  float mu = f;
  #pragma unroll
  for (int o = 16; o > 0; o >>= 1) mu += __shfl_xor(mu, o);
  mu *= (1.f/32.f);
  float d = f - mu;
  float v = d*d;
  #pragma unroll
  for (int o = 16; o > 0; o >>= 1) v += __shfl_xor(v, o);
  v *= (1.f/32.f);
  float is = g[j] / sqrtf(v + 1e-5f);
  if (b < 32) fn[b*673 + j] = d*is + be[j];
}

__global__ __launch_bounds__(512) void k_mlp1(const float* __restrict__ fn,
                                              const float* __restrict__ W1, const float* __restrict__ b1,
                                              float* __restrict__ h1o){
  int task = blockIdx.x*8 + (threadIdx.x >> 6);
  int lane = threadIdx.x & 63;
  if (task >= 32*300) return;
  int b = task / 300, r = task - b*300;
  const float* f = fn + b*673;
  const float* w = W1 + r*673;
  float acc = 0.f;
  for (int k = lane; k < 673; k += 64) acc = fmaf(f[k], w[k], acc);
  #pragma unroll
  for (int o = 32; o > 0; o >>= 1) acc += __shfl_down(acc, o);
  if (lane == 0) h1o[b*300 + r] = fmaxf(acc + b1[r], 0.f);
}

__global__ __launch_bounds__(512) void k_mlp2(const float* __restrict__ h1,
                                              const float* __restrict__ W2, const float* __restrict__ b2,
                                              float* __restrict__ h2o){
  int task = blockIdx.x*8 + (threadIdx.x >> 6);
  int lane = threadIdx.x & 63;
  if (task >= 32*90) return;
  int b = task / 90, r = task - b*90;
  const float* h = h1 + b*300;
  const float* w = W2 + r*300;
  float acc = 0.f;
  for (int k = lane; k < 300; k += 64) acc = fmaf(h[k], w[k], acc);
  #pragma unroll
  for (int o = 32; o > 0; o >>= 1) acc += __shfl_down(acc, o);
  if (lane == 0) h2o[b*90 + r] = fmaxf(acc + b2[r], 0.f);
}

__global__ __launch_bounds__(256) void k_mlp3(const float* __restrict__ h2,
                                              const float* __restrict__ W3, const float* __restrict__ b3,
                                              float* __restrict__ out){
  __shared__ float lg[35];
  int b = blockIdx.x;
  int tid = threadIdx.x, wid = tid >> 6, lane = tid & 63;
  for (int r = wid; r < 35; r += 4){
    float acc = 0.f;
    for (int k = lane; k < 90; k += 64) acc = fmaf(h2[b*90 + k], W3[r*90 + k], acc);
    #pragma unroll
    for (int o = 32; o > 0; o >>= 1) acc += __shfl_down(acc, o);
    if (lane == 0) lg[r] = acc + b3[r];
  }
  __syncthreads();
  if (tid < 64){
    float v = (tid < 35) ? lg[tid] : -1e30f;
    float mx = v;
    #pragma unroll
    for (int o = 32; o > 0; o >>= 1) mx = fmaxf(mx, __shfl_xor(mx, o));
    float e = (tid < 35) ? expf(v - mx) : 0.f;
    float se = e;
    #pragma unroll
    for (int o = 32; o > 0; o >>= 1) se += __shfl_xor(se, o);
    if (tid < 35) out[b*35 + tid] = v - mx - logf(se);
  }
}

// ---------------- host ----------------

extern "C" void kernel_launch(void* const* d_in, const int* in_sizes, int n_in,
                              void* d_out, int out_size, void* d_ws, size_t ws_size,
                              hipStream_t stream){
  const float* x     = (const float*)d_in[0];
  const float* psi1  = (const float*)d_in[1];
  const float* phi1  = (const float*)d_in[2];
  const float* psi2  = (const float*)d_in[3];
  const float* phi2  = (const float*)d_in[4];
  const float* gamma = (const float*)d_in[5];
  const float* beta  = (const float*)d_in[6];
  const float* W1    = (const float*)d_in[7];
  const float* b1    = (const float*)d_in[8];
  const float* W2    = (const float*)d_in[9];
  const float* b2    = (const float*)d_in[10];
  const float* W3    = (const float*)d_in[11];
  const float* b3    = (const float*)d_in[12];
  const int*   pi1   = (const int*)d_in[13];
  const int*   pi2   = (const int*)d_in[14];

  char* ws = (char*)d_ws;
  constexpr size_t o_tw = 0;
  constexpr size_t o_Xf = o_tw + (size_t)16000*sizeof(cf);
  constexpr size_t o_U  = o_Xf + (size_t)32*16000*sizeof(cf);
  constexpr size_t o_S1 = o_U  + (size_t)3840*2000*sizeof(cf);
  constexpr size_t o_S2 = o_S1 + (size_t)3840*16*sizeof(float);
  constexpr size_t o_l5 = o_S2 + (size_t)17696*16*sizeof(float);
  constexpr size_t o_l4 = o_l5 + (size_t)512*sizeof(int);
  constexpr size_t o_fn = o_l4 + (size_t)64*sizeof(int);
  constexpr size_t o_h1 = o_fn + (size_t)32*673*sizeof(float);
  constexpr size_t o_h2 = o_h1 + (size_t)5202*sizeof(float);
  constexpr size_t o_m1 = o_h2 + (size_t)662*sizeof(float);
  constexpr size_t o_m2 = o_m1 + (size_t)32*300*sizeof(float);

  cf*    tw    = (cf*)(ws + o_tw);
  cf*    Xf    = (cf*)(ws + o_Xf);
  cf*    U1sf  = (cf*)(ws + o_U);
  float* S1b   = (float*)(ws + o_S1);
  float* S2b   = (float*)(ws + o_S2);
  int*   list5 = (int*)(ws + o_l5);
  int*   list4 = (int*)(ws + o_l4);
  float* fnbuf = (float*)(ws + o_fn);
  float* h1g   = (float*)(ws + o_h1);
  float* h2g   = (float*)(ws + o_h2);
  float* m1buf = (float*)(ws + o_m1);
  float* m2buf = (float*)(ws + o_m2);

  hipFuncSetAttribute((const void*)kf<16000,1,13, 0,1024>, hipFuncAttributeMaxDynamicSharedMemorySize, 131072);
  hipFuncSetAttribute((const void*)kf< 8000,2,10,13,1024>, hipFuncAttributeMaxDynamicSharedMemorySize, 131072);

  k_tw<<<63, 256, 0, stream>>>(tw);
  k_btab<<<23, 256, 0, stream>>>(phi1, phi2, h1g, h2g);
  k_classify<<<1, 1024, 0, stream>>>(pi2, list5, list4);
  k_fftx4<<<128, 512, 4000*8, stream>>>(x, Xf, tw);
  kf<16000,1,13, 0,1024><<<32*13, 1024, 16000*8 + 17*4, stream>>>(Xf, psi1, h1g, tw, U1sf, S1b);
  kf< 8000,2,10,13,1024><<<32*10, 1024,  8000*8 + 17*4, stream>>>(Xf, psi1, h1g, tw, U1sf, S1b);
  kf< 4000,4,10,23,1024><<<32*10, 1024,  4000*8 + 17*4, stream>>>(Xf, psi1, h1g, tw, U1sf, S1b);
  k_n2<2000,10,33><<<32*10, 256, 2000*8, stream>>>(Xf, psi1, phi1, tw, U1sf, S1b);
  k_n2<1600,10,43><<<32*10, 256, 1600*8, stream>>>(Xf, psi1, phi1, tw, U1sf, S1b);
  k_nw2<640,640,10,53,4><<< 80, 256, 4*640*8, stream>>>(Xf, psi1, phi1, tw, U1sf, S1b);
  k_nw2<320,320,10,63,8><<< 40, 512, 8*320*8, stream>>>(Xf, psi1, phi1, tw, U1sf, S1b);
  k_nw2<200,208,10,73,8><<< 40, 512, 8*208*8, stream>>>(Xf, psi1, phi1, tw, U1sf, S1b);
  k_nw2<160,160,37,83,8><<<148, 512, 8*160*8, stream>>>(Xf, psi1, phi1, tw, U1sf, S1b);
  k_sec5<<<(493*32)/4, 256, 0, stream>>>(U1sf, psi2, h2g, tw, pi1, pi2, list5, S2b);
  k_secbig<<<60*32, 128, 2000*8 + 2000*4 + 4*4, stream>>>(U1sf, psi2, h2g, tw, pi1, pi2, list4, S2b);
  k_fbn<<<673, 64, 0, stream>>>(S1b, S2b, gamma, beta, fnbuf);
  k_mlp1<<<1200, 512, 0, stream>>>(fnbuf, W1, b1, m1buf);
  k_mlp2<<<360, 512, 0, stream>>>(m1buf, W2, b2, m2buf);
  k_mlp3<<<32, 256, 0, stream>>>(m2buf, W3, b3, (float*)d_out);
}